// Round 3
// baseline (490.005 us; speedup 1.0000x reference)
//
#include <hip/hip_runtime.h>
#include <math.h>

#define N_NODES 50000
#define NP 50048          // padded to multiple of 64 for GEMM tiles
#define F_IN 128
#define HD 256            // HEADS*D_HEAD
#define HID 256
#define NE 800000
#define CAP 64
#define NEG_SLOPE 0.2f
#define G1_BLOCKS (NP / 64)       // 782 gemm1 blocks in the combined launch
#define FILL_BLOCKS ((NE + 1023) / 1024)   // 782 fill blocks, 4 edges/thread
#define CNT_STRIDE 4              // 16B/counter: mild anti-contention

#define PAIRS (N_NODES / 2)       // 25000 node pairs per column group
#define CHUNK_PAIRS 32            // pairs per cursor grab (8 pairs/wave)
#define GAT_BLOCKS 2048           // 8 blocks/CU, 4 waves each -> full CU occupancy

typedef __attribute__((ext_vector_type(8))) __bf16 bf16x8;
typedef __attribute__((ext_vector_type(4))) __bf16 bf16x4;
typedef __attribute__((ext_vector_type(4))) float f32x4;

#define GLD_LDS16(g, l)                                                      \
    __builtin_amdgcn_global_load_lds(                                        \
        (const __attribute__((address_space(1))) unsigned int*)(g),          \
        (__attribute__((address_space(3))) unsigned int*)(l), 16, 0, 0)

// ---------------------------------------------------------------------------
// prep: cnt/bucket/cursor init + 3 weight transposes. One launch.
#define PB_INIT 196
#define PB_WG   128
#define PB_W1   256
#define PB_W2   256

__global__ __launch_bounds__(256) void prep_kernel(const float* __restrict__ Wg,
                                                   const float* __restrict__ W1,
                                                   const float* __restrict__ W2,
                                                   __bf16* __restrict__ Wg_t,
                                                   __bf16* __restrict__ W1_t,
                                                   __bf16* __restrict__ W2_t,
                                                   int* __restrict__ cnt,
                                                   unsigned short* __restrict__ bucket,
                                                   int* __restrict__ cursors) {
    int b = blockIdx.x, t = threadIdx.x;
    if (b < PB_INIT) {
        if (b == 0 && t < 8) cursors[t] = 0;
        int n = b * 256 + t;
        if (n < N_NODES) { cnt[(size_t)n * CNT_STRIDE] = 1; bucket[n * CAP] = (unsigned short)n; }
    } else if (b < PB_INIT + PB_WG) {
        int i = (b - PB_INIT) * 256 + t;             // 32768 = HD*F_IN
        int m = i >> 7, k = i & 127;
        Wg_t[i] = (__bf16)Wg[(size_t)k * HD + m];
    } else if (b < PB_INIT + PB_WG + PB_W1) {
        int i = (b - PB_INIT - PB_WG) * 256 + t;     // 65536
        int m = i >> 8, k = i & 255;
        W1_t[i] = (__bf16)W1[(size_t)k * HID + m];
    } else {
        int i = (b - PB_INIT - PB_WG - PB_W1) * 256 + t;
        int m = i >> 8, k = i & 255;
        W2_t[i] = (__bf16)W2[(size_t)k * HID + m];
    }
}

// ---------------------------------------------------------------------------
// Combined launch: blocks [0, G1_BLOCKS) run GEMM1 (x @ W_gat, fused fp32->
// bf16 convert + attention coefficients); blocks [G1_BLOCKS, +FILL_BLOCKS)
// run the edge-bucket fill (4 edges/thread for 4 independent atomic chains).
__global__ __launch_bounds__(256) void g1_fill_kernel(const float* __restrict__ x,
                                                      const __bf16* __restrict__ Bt,
                                                      const float* __restrict__ att_src,
                                                      const float* __restrict__ att_dst,
                                                      const int* __restrict__ ew,
                                                      __bf16* __restrict__ h,
                                                      float* __restrict__ a_s,
                                                      float* __restrict__ a_d,
                                                      int* __restrict__ cnt,
                                                      unsigned short* __restrict__ bucket) {
    __shared__ __bf16 As[64 * 32];    // [row][k]
    __shared__ __bf16 Bs[256 * 32];   // [col][k]

    if (blockIdx.x >= G1_BLOCKS) {
        // ---- fill branch, ILP-4: int64-vs-int32 detection via per-wave
        // ballot of high words (int64 => all high words zero). u16 bucket.
        const int base = (blockIdx.x - G1_BLOCKS) * 1024 + threadIdx.x;
        const int e0 = base, e1 = base + 256, e2 = base + 512, e3 = base + 768;
        const bool v0 = e0 < NE, v1 = e1 < NE, v2 = e2 < NE, v3 = e3 < NE;
        long long p0 = 0, p1 = 0, p2 = 0, p3 = 0;
        if (v0) p0 = *(const long long*)&ew[2 * e0];
        if (v1) p1 = *(const long long*)&ew[2 * e1];
        if (v2) p2 = *(const long long*)&ew[2 * e2];
        if (v3) p3 = *(const long long*)&ew[2 * e3];
        const int hiall = (int)(p0 >> 32) | (int)(p1 >> 32) |
                          (int)(p2 >> 32) | (int)(p3 >> 32);
        unsigned long long bal = __ballot(hiall != 0);
        int s0 = 0, s1 = 0, s2 = 0, s3 = 0, d0 = 0, d1 = 0, d2 = 0, d3 = 0;
        if (bal == 0) {   // int64 layout: pair (lo,hi) per value
            s0 = (int)p0; s1 = (int)p1; s2 = (int)p2; s3 = (int)p3;
            if (v0) d0 = ew[2 * NE + 2 * e0];
            if (v1) d1 = ew[2 * NE + 2 * e1];
            if (v2) d2 = ew[2 * NE + 2 * e2];
            if (v3) d3 = ew[2 * NE + 2 * e3];
        } else {          // int32 layout
            if (v0) { s0 = ew[e0]; d0 = ew[NE + e0]; }
            if (v1) { s1 = ew[e1]; d1 = ew[NE + e1]; }
            if (v2) { s2 = ew[e2]; d2 = ew[NE + e2]; }
            if (v3) { s3 = ew[e3]; d3 = ew[NE + e3]; }
        }
        int pos0 = CAP, pos1 = CAP, pos2 = CAP, pos3 = CAP;
        if (v0) pos0 = atomicAdd(&cnt[(size_t)d0 * CNT_STRIDE], 1);
        if (v1) pos1 = atomicAdd(&cnt[(size_t)d1 * CNT_STRIDE], 1);
        if (v2) pos2 = atomicAdd(&cnt[(size_t)d2 * CNT_STRIDE], 1);
        if (v3) pos3 = atomicAdd(&cnt[(size_t)d3 * CNT_STRIDE], 1);
        if (pos0 < CAP) bucket[d0 * CAP + pos0] = (unsigned short)s0;
        if (pos1 < CAP) bucket[d1 * CAP + pos1] = (unsigned short)s1;
        if (pos2 < CAP) bucket[d2 * CAP + pos2] = (unsigned short)s2;
        if (pos3 < CAP) bucket[d3 * CAP + pos3] = (unsigned short)s3;
        return;
    }

    // ---- GEMM1 branch: tile 64 rows x 256 cols, 4 waves (col_off = head*64)
    const int t = threadIdx.x;
    const int lane = t & 63, wv = t >> 6;
    const int lr = lane & 15, q = lane >> 4, lk = q * 8;
    const int col_off = wv * 64;
    const int row0 = blockIdx.x * 64;
    const int sr = t >> 2, sk = (t & 3) * 8;
    const int arow = row0 + sr;
    const bool avalid = arow < N_NODES;

    f32x4 acc[4][4];
#pragma unroll
    for (int r = 0; r < 4; ++r)
#pragma unroll
        for (int c = 0; c < 4; ++c) acc[r][c] = f32x4{0.f, 0.f, 0.f, 0.f};

    for (int k0 = 0; k0 < F_IN; k0 += 32) {
        // A staging: load x fp32, convert to bf16, ds_write (fused convert)
        float4 v0 = {0, 0, 0, 0}, v1 = {0, 0, 0, 0};
        if (avalid) {
            const float* xp = &x[(size_t)arow * F_IN + k0 + sk];
            v0 = *(const float4*)xp;
            v1 = *(const float4*)(xp + 4);
        }
        bf16x8 o;
        o[0] = (__bf16)v0.x; o[1] = (__bf16)v0.y; o[2] = (__bf16)v0.z; o[3] = (__bf16)v0.w;
        o[4] = (__bf16)v1.x; o[5] = (__bf16)v1.y; o[6] = (__bf16)v1.z; o[7] = (__bf16)v1.w;
        *(bf16x8*)&As[sr * 32 + sk] = o;
        // B staging: async global->LDS
#pragma unroll
        for (int s = 0; s < 4; ++s) {
            int r = s * 64 + sr;
            GLD_LDS16(&Bt[(size_t)r * F_IN + k0 + sk], &Bs[r * 32 + sk]);
        }
        __syncthreads();
        bf16x8 af[4], bfr[4];
#pragma unroll
        for (int i = 0; i < 4; ++i) {
            af[i]  = *(const bf16x8*)&As[(i * 16 + lr) * 32 + lk];
            bfr[i] = *(const bf16x8*)&Bs[(col_off + i * 16 + lr) * 32 + lk];
        }
#pragma unroll
        for (int r = 0; r < 4; ++r)
#pragma unroll
            for (int c = 0; c < 4; ++c)
                acc[r][c] = __builtin_amdgcn_mfma_f32_16x16x32_bf16(af[r], bfr[c], acc[r][c], 0, 0, 0);
        __syncthreads();
    }

    float asv[4], adv[4];
#pragma unroll
    for (int c = 0; c < 4; ++c) {
        int col = col_off + c * 16 + lr;
        asv[c] = att_src[col];
        adv[c] = att_dst[col];
    }
    float ps[4][4], pd[4][4];
#pragma unroll
    for (int r = 0; r < 4; ++r)
#pragma unroll
        for (int i = 0; i < 4; ++i) { ps[r][i] = 0.f; pd[r][i] = 0.f; }

#pragma unroll
    for (int c = 0; c < 4; ++c) {
        int col = col_off + c * 16 + lr;
#pragma unroll
        for (int r = 0; r < 4; ++r) {
#pragma unroll
            for (int i = 0; i < 4; ++i) {
                int row = row0 + r * 16 + q * 4 + i;   // < NP by construction
                float v = acc[r][c][i];
                h[(size_t)row * HD + col] = (__bf16)v;
                ps[r][i] += v * asv[c];
                pd[r][i] += v * adv[c];
            }
        }
    }
#pragma unroll
    for (int r = 0; r < 4; ++r)
#pragma unroll
        for (int i = 0; i < 4; ++i) {
#pragma unroll
            for (int m = 1; m < 16; m <<= 1) {
                ps[r][i] += __shfl_xor(ps[r][i], m);
                pd[r][i] += __shfl_xor(pd[r][i], m);
            }
        }
    if (lr == 0) {
#pragma unroll
        for (int r = 0; r < 4; ++r)
#pragma unroll
            for (int i = 0; i < 4; ++i) {
                int row = row0 + r * 16 + q * 4 + i;
                a_s[row * 4 + wv] = ps[r][i];
                a_d[row * 4 + wv] = pd[r][i];
            }
    }
}

__device__ __forceinline__ float lrelu(float v) { return v >= 0.f ? v : NEG_SLOPE * v; }

// ---------------------------------------------------------------------------
// Fused per-destination softmax + weighted gather-aggregate, XCD-column-sharded
// with PHYSICAL pinning: each block reads its XCD id via s_getreg(HW_REG_XCC_ID)
// and preferentially pulls work for column group g == xcd from a per-group
// atomic cursor (work-stealing across groups once its own is drained, so
// correctness never depends on the hwreg value or the scheduler). Per XCD the
// hot h-slice is 50K rows x 64B = 3.2MB < 4MB L2. Softmax is recomputed per
// group (only the group's single head). Inner gather uses 16B bf16x8 loads:
// 8 source-slots x 4 lanes x 8 cols per 32-lane half (one node per half).
__global__ __launch_bounds__(256) void gat_aggregate_kernel(const __bf16* __restrict__ h,
                                                            const float* __restrict__ a_s,
                                                            const float* __restrict__ a_d,
                                                            const int* __restrict__ cnt,
                                                            const unsigned short* __restrict__ bucket,
                                                            const float* __restrict__ b_gat,
                                                            __bf16* __restrict__ gat,
                                                            int* __restrict__ cursors) {
    __shared__ unsigned short s_src[4][128];   // per-wave [half*64 + j]
    __shared__ float s_alpha[4][128];
    __shared__ int s_chunk;

    const int t = threadIdx.x;
    const int wv = t >> 6, lane = t & 63;
    const int half = lane >> 5, l32 = lane & 31;
    const int slot = l32 >> 2;        // 0..7 source slot
    const int cq = l32 & 3;           // 0..3 -> 8 cols each

    // physical XCD id (hwreg 20). Wrong value only costs locality, never
    // correctness (work ownership comes from the cursors).
    const int my_xcd = (int)(__builtin_amdgcn_s_getreg(63508) & 7u);

    for (int gi = 0; gi < 8; ++gi) {
        const int g = (my_xcd + gi) & 7;   // column group; own XCD first
        const int head = g >> 1;
        const int c0 = g * 32;
        for (;;) {
            __syncthreads();               // prior s_chunk reads complete
            if (t == 0) s_chunk = atomicAdd(&cursors[g], CHUNK_PAIRS);
            __syncthreads();
            const int p0 = s_chunk;
            if (p0 >= PAIRS) break;        // uniform across block

            for (int pp = wv; pp < CHUNK_PAIRS; pp += 4) {
                const int pair = p0 + pp;
                if (pair >= PAIRS) break;
                const int n = pair * 2 + half;

                int deg = cnt[(size_t)n * CNT_STRIDE];
                if (deg > CAP) deg = CAP;
                const float ad = a_d[n * 4 + head];

                int src0 = n, src1 = n;
                float e0 = -1e30f, e1 = -1e30f;
                if (l32 < deg) {
                    src0 = bucket[n * CAP + l32];
                    e0 = lrelu(a_s[src0 * 4 + head] + ad);
                }
                if (l32 + 32 < deg) {
                    src1 = bucket[n * CAP + l32 + 32];
                    e1 = lrelu(a_s[src1 * 4 + head] + ad);
                }
                float m = fmaxf(e0, e1);
#pragma unroll
                for (int off = 1; off < 32; off <<= 1) m = fmaxf(m, __shfl_xor(m, off));
                float w0 = (l32 < deg) ? __expf(e0 - m) : 0.f;
                float w1 = (l32 + 32 < deg) ? __expf(e1 - m) : 0.f;
                float s = w0 + w1;
#pragma unroll
                for (int off = 1; off < 32; off <<= 1) s += __shfl_xor(s, off);
                const float inv = 1.f / s;
                s_src[wv][half * 64 + l32] = (unsigned short)src0;
                s_src[wv][half * 64 + l32 + 32] = (unsigned short)src1;
                s_alpha[wv][half * 64 + l32] = w0 * inv;
                s_alpha[wv][half * 64 + l32 + 32] = w1 * inv;
                // wave-private LDS region; DS ops from one wave complete
                // in order, but make the W->R ordering explicit:
                asm volatile("s_waitcnt lgkmcnt(0)" ::: "memory");

                float acc[8];
#pragma unroll
                for (int k = 0; k < 8; ++k) acc[k] = 0.f;
                const int hb = c0 + cq * 8;
                for (int j = slot; j < deg; j += 8) {
                    const int sj = s_src[wv][half * 64 + j];
                    const float aj = s_alpha[wv][half * 64 + j];
                    const bf16x8 hv = *(const bf16x8*)&h[(size_t)sj * HD + hb];
#pragma unroll
                    for (int k = 0; k < 8; ++k) acc[k] += aj * (float)hv[k];
                }
                // reduce across the 8 slots (lane bits 2,3,4 within the half)
#pragma unroll
                for (int k = 0; k < 8; ++k) {
                    acc[k] += __shfl_xor(acc[k], 4);
                    acc[k] += __shfl_xor(acc[k], 8);
                    acc[k] += __shfl_xor(acc[k], 16);
                }
                if (slot == 0) {           // 4 lanes x 16B = 64B per node-group
                    const float4 bg0 = *(const float4*)&b_gat[hb];
                    const float4 bg1 = *(const float4*)&b_gat[hb + 4];
                    bf16x8 o;
                    o[0] = (__bf16)(acc[0] + bg0.x); o[1] = (__bf16)(acc[1] + bg0.y);
                    o[2] = (__bf16)(acc[2] + bg0.z); o[3] = (__bf16)(acc[3] + bg0.w);
                    o[4] = (__bf16)(acc[4] + bg1.x); o[5] = (__bf16)(acc[5] + bg1.y);
                    o[6] = (__bf16)(acc[6] + bg1.z); o[7] = (__bf16)(acc[7] + bg1.w);
                    *(bf16x8*)&gat[(size_t)n * HD + hb] = o;
                }
            }
        }
    }
}

// ---------------------------------------------------------------------------
// Fused MLP: out = relu(relu(gat@W1+b1)@W2+b2)@W3 + b3, one kernel.
__global__ __launch_bounds__(256) void fused_mlp_kernel(const __bf16* __restrict__ A,
                                                        const __bf16* __restrict__ W1t,
                                                        const __bf16* __restrict__ W2t,
                                                        const float* __restrict__ b1,
                                                        const float* __restrict__ b2,
                                                        const float* __restrict__ W3,
                                                        const float* __restrict__ b3,
                                                        float* __restrict__ out) {
    __shared__ __bf16 As[64 * 32];        // 4 KB
    __shared__ __bf16 Ws[256 * 32];       // 16 KB
    __shared__ __bf16 h1s[8 * 64 * 32];   // 32 KB, chunk c holds k in [32c,32c+32)
    __shared__ float s_out[64][2];
    const int t = threadIdx.x;
    const int lane = t & 63, wv = t >> 6;
    const int lr = lane & 15, q = lane >> 4, lk = q * 8;
    const int col_off = wv * 64;
    const int row0 = blockIdx.x * 64;
    const int sr = t >> 2, sk = (t & 3) * 8;

    if (t < 128) ((float*)s_out)[t] = 0.f;

    f32x4 acc[4][4];
#pragma unroll
    for (int r = 0; r < 4; ++r)
#pragma unroll
        for (int c = 0; c < 4; ++c) acc[r][c] = f32x4{0.f, 0.f, 0.f, 0.f};

    // ---- stage 1: h1 = relu(gat @ W1 + b1) -> LDS
    for (int k0 = 0; k0 < HD; k0 += 32) {
        GLD_LDS16(&A[(size_t)(row0 + sr) * HD + k0 + sk], &As[sr * 32 + sk]);
#pragma unroll
        for (int s = 0; s < 4; ++s) {
            int r = s * 64 + sr;
            GLD_LDS16(&W1t[(size_t)r * HD + k0 + sk], &Ws[r * 32 + sk]);
        }
        __syncthreads();
        bf16x8 af[4], bfr[4];
#pragma unroll
        for (int i = 0; i < 4; ++i) {
            af[i]  = *(const bf16x8*)&As[(i * 16 + lr) * 32 + lk];
            bfr[i] = *(const bf16x8*)&Ws[(col_off + i * 16 + lr) * 32 + lk];
        }
#pragma unroll
        for (int r = 0; r < 4; ++r)
#pragma unroll
            for (int c = 0; c < 4; ++c)
                acc[r][c] = __builtin_amdgcn_mfma_f32_16x16x32_bf16(af[r], bfr[c], acc[r][c], 0, 0, 0);
        __syncthreads();
    }
#pragma unroll
    for (int c = 0; c < 4; ++c) {
        int col = col_off + c * 16 + lr;
        float bv = b1[col];
        int cb = (col >> 5) * 2048;
        int kk = col & 31;
#pragma unroll
        for (int r = 0; r < 4; ++r)
#pragma unroll
            for (int i = 0; i < 4; ++i) {
                int row = r * 16 + q * 4 + i;
                float v = fmaxf(acc[r][c][i] + bv, 0.f);
                h1s[cb + row * 32 + kk] = (__bf16)v;
                acc[r][c][i] = 0.f;
            }
    }
    __syncthreads();

    // ---- stage 2: h2 = h1 @ W2
    for (int k0 = 0; k0 < HID; k0 += 32) {
#pragma unroll
        for (int s = 0; s < 4; ++s) {
            int r = s * 64 + sr;
            GLD_LDS16(&W2t[(size_t)r * HID + k0 + sk], &Ws[r * 32 + sk]);
        }
        __syncthreads();
        const int cb = (k0 >> 5) * 2048;
        bf16x8 af[4], bfr[4];
#pragma unroll
        for (int i = 0; i < 4; ++i) {
            af[i]  = *(const bf16x8*)&h1s[cb + (i * 16 + lr) * 32 + lk];
            bfr[i] = *(const bf16x8*)&Ws[(col_off + i * 16 + lr) * 32 + lk];
        }
#pragma unroll
        for (int r = 0; r < 4; ++r)
#pragma unroll
            for (int c = 0; c < 4; ++c)
                acc[r][c] = __builtin_amdgcn_mfma_f32_16x16x32_bf16(af[r], bfr[c], acc[r][c], 0, 0, 0);
        __syncthreads();
    }

    // ---- stage 3: out = relu(h2+b2) @ W3 + b3 (fp32 throughout)
    float b2v[4], w30[4], w31[4];
#pragma unroll
    for (int c = 0; c < 4; ++c) {
        int col = col_off + c * 16 + lr;
        b2v[c] = b2[col];
        w30[c] = W3[col * 2];
        w31[c] = W3[col * 2 + 1];
    }
#pragma unroll
    for (int r = 0; r < 4; ++r) {
#pragma unroll
        for (int i = 0; i < 4; ++i) {
            float o0 = 0.f, o1 = 0.f;
#pragma unroll
            for (int c = 0; c < 4; ++c) {
                float v = fmaxf(acc[r][c][i] + b2v[c], 0.f);
                o0 += v * w30[c];
                o1 += v * w31[c];
            }
#pragma unroll
            for (int m = 1; m < 16; m <<= 1) {
                o0 += __shfl_xor(o0, m);
                o1 += __shfl_xor(o1, m);
            }
            if (lr == 0) {
                int row = r * 16 + q * 4 + i;
                atomicAdd(&s_out[row][0], o0);
                atomicAdd(&s_out[row][1], o1);
            }
        }
    }
    __syncthreads();
    if (t < 128) {
        int row = t >> 1, o = t & 1;
        int g = row0 + row;
        if (g < N_NODES) out[g * 2 + o] = s_out[row][o] + b3[o];
    }
}

// ---------------------------------------------------------------------------
extern "C" void kernel_launch(void* const* d_in, const int* in_sizes, int n_in,
                              void* d_out, int out_size, void* d_ws, size_t ws_size,
                              hipStream_t stream) {
    const float* x       = (const float*)d_in[0];
    const int*   ei      = (const int*)d_in[1];
    const float* W_gat   = (const float*)d_in[2];
    const float* att_src = (const float*)d_in[3];
    const float* att_dst = (const float*)d_in[4];
    const float* b_gat   = (const float*)d_in[5];
    const float* W1      = (const float*)d_in[6];
    const float* b1      = (const float*)d_in[7];
    const float* W2      = (const float*)d_in[8];
    const float* b2      = (const float*)d_in[9];
    const float* W3      = (const float*)d_in[10];
    const float* b3      = (const float*)d_in[11];
    float* out = (float*)d_out;

    char* ws = (char*)d_ws;
    __bf16* h_bf   = (__bf16*)ws;  ws += (size_t)NP * HD * 2;
    __bf16* gat_bf = (__bf16*)ws;  ws += (size_t)NP * HD * 2;
    __bf16* Wg_t   = (__bf16*)ws;  ws += (size_t)HD * F_IN * 2;
    __bf16* W1_t   = (__bf16*)ws;  ws += (size_t)HID * HD * 2;
    __bf16* W2_t   = (__bf16*)ws;  ws += (size_t)HID * HID * 2;
    float* a_s     = (float*)ws;   ws += (size_t)NP * 4 * 4;
    float* a_d     = (float*)ws;   ws += (size_t)NP * 4 * 4;
    int* cnt       = (int*)ws;     ws += (size_t)N_NODES * CNT_STRIDE * 4;
    int* cursors   = (int*)ws;     ws += 64;   // 8 cursors, 64B padded
    unsigned short* bucket = (unsigned short*)ws;
    ws += (size_t)N_NODES * CAP * 2;

    prep_kernel<<<PB_INIT + PB_WG + PB_W1 + PB_W2, 256, 0, stream>>>(
        W_gat, W1, W2, Wg_t, W1_t, W2_t, cnt, bucket, cursors);
    g1_fill_kernel<<<G1_BLOCKS + FILL_BLOCKS, 256, 0, stream>>>(
        x, Wg_t, att_src, att_dst, ei, h_bf, a_s, a_d, cnt, bucket);
    gat_aggregate_kernel<<<GAT_BLOCKS, 256, 0, stream>>>(h_bf, a_s, a_d, cnt, bucket,
                                                         b_gat, gat_bf, cursors);
    fused_mlp_kernel<<<NP / 64, 256, 0, stream>>>(gat_bf, W1_t, W2_t, b1, b2, W3, b3, out);
}

// Round 4
// 290.627 us; speedup vs baseline: 1.6860x; 1.6860x over previous
//
#include <hip/hip_runtime.h>
#include <math.h>

#define N_NODES 50000
#define NP 50048          // padded to multiple of 64 for GEMM tiles
#define F_IN 128
#define HD 256            // HEADS*D_HEAD
#define HID 256
#define NE 800000
#define CAP 64
#define NEG_SLOPE 0.2f
#define G1_BLOCKS (NP / 64)       // 782 gemm1 blocks in the combined launch
#define FILL_BLOCKS ((NE + 1023) / 1024)   // 782 fill blocks, 4 edges/thread
#define CNT_STRIDE 4              // 16B/counter: mild anti-contention

typedef __attribute__((ext_vector_type(8))) __bf16 bf16x8;
typedef __attribute__((ext_vector_type(4))) __bf16 bf16x4;
typedef __attribute__((ext_vector_type(4))) float f32x4;

#define GLD_LDS16(g, l)                                                      \
    __builtin_amdgcn_global_load_lds(                                        \
        (const __attribute__((address_space(1))) unsigned int*)(g),          \
        (__attribute__((address_space(3))) unsigned int*)(l), 16, 0, 0)

// ---------------------------------------------------------------------------
// prep: cnt/bucket init + 3 weight transposes. One launch.
#define PB_INIT 196
#define PB_WG   128
#define PB_W1   256
#define PB_W2   256

__global__ __launch_bounds__(256) void prep_kernel(const float* __restrict__ Wg,
                                                   const float* __restrict__ W1,
                                                   const float* __restrict__ W2,
                                                   __bf16* __restrict__ Wg_t,
                                                   __bf16* __restrict__ W1_t,
                                                   __bf16* __restrict__ W2_t,
                                                   int* __restrict__ cnt,
                                                   unsigned short* __restrict__ bucket) {
    int b = blockIdx.x, t = threadIdx.x;
    if (b < PB_INIT) {
        int n = b * 256 + t;
        if (n < N_NODES) { cnt[(size_t)n * CNT_STRIDE] = 1; bucket[n * CAP] = (unsigned short)n; }
    } else if (b < PB_INIT + PB_WG) {
        int i = (b - PB_INIT) * 256 + t;             // 32768 = HD*F_IN
        int m = i >> 7, k = i & 127;
        Wg_t[i] = (__bf16)Wg[(size_t)k * HD + m];
    } else if (b < PB_INIT + PB_WG + PB_W1) {
        int i = (b - PB_INIT - PB_WG) * 256 + t;     // 65536
        int m = i >> 8, k = i & 255;
        W1_t[i] = (__bf16)W1[(size_t)k * HID + m];
    } else {
        int i = (b - PB_INIT - PB_WG - PB_W1) * 256 + t;
        int m = i >> 8, k = i & 255;
        W2_t[i] = (__bf16)W2[(size_t)k * HID + m];
    }
}

// ---------------------------------------------------------------------------
// Combined launch: blocks [0, G1_BLOCKS) run GEMM1 (x @ W_gat, fused fp32->
// bf16 convert + attention coefficients); blocks [G1_BLOCKS, +FILL_BLOCKS)
// run the edge-bucket fill (4 edges/thread for 4 independent atomic chains).
__global__ __launch_bounds__(256) void g1_fill_kernel(const float* __restrict__ x,
                                                      const __bf16* __restrict__ Bt,
                                                      const float* __restrict__ att_src,
                                                      const float* __restrict__ att_dst,
                                                      const int* __restrict__ ew,
                                                      __bf16* __restrict__ h,
                                                      float* __restrict__ a_s,
                                                      float* __restrict__ a_d,
                                                      int* __restrict__ cnt,
                                                      unsigned short* __restrict__ bucket) {
    __shared__ __bf16 As[64 * 32];    // [row][k]
    __shared__ __bf16 Bs[256 * 32];   // [col][k]

    if (blockIdx.x >= G1_BLOCKS) {
        // ---- fill branch, ILP-4: int64-vs-int32 detection via per-wave
        // ballot of high words (int64 => all high words zero). u16 bucket.
        const int base = (blockIdx.x - G1_BLOCKS) * 1024 + threadIdx.x;
        const int e0 = base, e1 = base + 256, e2 = base + 512, e3 = base + 768;
        const bool v0 = e0 < NE, v1 = e1 < NE, v2 = e2 < NE, v3 = e3 < NE;
        long long p0 = 0, p1 = 0, p2 = 0, p3 = 0;
        if (v0) p0 = *(const long long*)&ew[2 * e0];
        if (v1) p1 = *(const long long*)&ew[2 * e1];
        if (v2) p2 = *(const long long*)&ew[2 * e2];
        if (v3) p3 = *(const long long*)&ew[2 * e3];
        const int hiall = (int)(p0 >> 32) | (int)(p1 >> 32) |
                          (int)(p2 >> 32) | (int)(p3 >> 32);
        unsigned long long bal = __ballot(hiall != 0);
        int s0 = 0, s1 = 0, s2 = 0, s3 = 0, d0 = 0, d1 = 0, d2 = 0, d3 = 0;
        if (bal == 0) {   // int64 layout: pair (lo,hi) per value
            s0 = (int)p0; s1 = (int)p1; s2 = (int)p2; s3 = (int)p3;
            if (v0) d0 = ew[2 * NE + 2 * e0];
            if (v1) d1 = ew[2 * NE + 2 * e1];
            if (v2) d2 = ew[2 * NE + 2 * e2];
            if (v3) d3 = ew[2 * NE + 2 * e3];
        } else {          // int32 layout
            if (v0) { s0 = ew[e0]; d0 = ew[NE + e0]; }
            if (v1) { s1 = ew[e1]; d1 = ew[NE + e1]; }
            if (v2) { s2 = ew[e2]; d2 = ew[NE + e2]; }
            if (v3) { s3 = ew[e3]; d3 = ew[NE + e3]; }
        }
        int pos0 = CAP, pos1 = CAP, pos2 = CAP, pos3 = CAP;
        if (v0) pos0 = atomicAdd(&cnt[(size_t)d0 * CNT_STRIDE], 1);
        if (v1) pos1 = atomicAdd(&cnt[(size_t)d1 * CNT_STRIDE], 1);
        if (v2) pos2 = atomicAdd(&cnt[(size_t)d2 * CNT_STRIDE], 1);
        if (v3) pos3 = atomicAdd(&cnt[(size_t)d3 * CNT_STRIDE], 1);
        if (pos0 < CAP) bucket[d0 * CAP + pos0] = (unsigned short)s0;
        if (pos1 < CAP) bucket[d1 * CAP + pos1] = (unsigned short)s1;
        if (pos2 < CAP) bucket[d2 * CAP + pos2] = (unsigned short)s2;
        if (pos3 < CAP) bucket[d3 * CAP + pos3] = (unsigned short)s3;
        return;
    }

    // ---- GEMM1 branch: tile 64 rows x 256 cols, 4 waves (col_off = head*64)
    const int t = threadIdx.x;
    const int lane = t & 63, wv = t >> 6;
    const int lr = lane & 15, q = lane >> 4, lk = q * 8;
    const int col_off = wv * 64;
    const int row0 = blockIdx.x * 64;
    const int sr = t >> 2, sk = (t & 3) * 8;
    const int arow = row0 + sr;
    const bool avalid = arow < N_NODES;

    f32x4 acc[4][4];
#pragma unroll
    for (int r = 0; r < 4; ++r)
#pragma unroll
        for (int c = 0; c < 4; ++c) acc[r][c] = f32x4{0.f, 0.f, 0.f, 0.f};

    for (int k0 = 0; k0 < F_IN; k0 += 32) {
        // A staging: load x fp32, convert to bf16, ds_write (fused convert)
        float4 v0 = {0, 0, 0, 0}, v1 = {0, 0, 0, 0};
        if (avalid) {
            const float* xp = &x[(size_t)arow * F_IN + k0 + sk];
            v0 = *(const float4*)xp;
            v1 = *(const float4*)(xp + 4);
        }
        bf16x8 o;
        o[0] = (__bf16)v0.x; o[1] = (__bf16)v0.y; o[2] = (__bf16)v0.z; o[3] = (__bf16)v0.w;
        o[4] = (__bf16)v1.x; o[5] = (__bf16)v1.y; o[6] = (__bf16)v1.z; o[7] = (__bf16)v1.w;
        *(bf16x8*)&As[sr * 32 + sk] = o;
        // B staging: async global->LDS
#pragma unroll
        for (int s = 0; s < 4; ++s) {
            int r = s * 64 + sr;
            GLD_LDS16(&Bt[(size_t)r * F_IN + k0 + sk], &Bs[r * 32 + sk]);
        }
        __syncthreads();
        bf16x8 af[4], bfr[4];
#pragma unroll
        for (int i = 0; i < 4; ++i) {
            af[i]  = *(const bf16x8*)&As[(i * 16 + lr) * 32 + lk];
            bfr[i] = *(const bf16x8*)&Bs[(col_off + i * 16 + lr) * 32 + lk];
        }
#pragma unroll
        for (int r = 0; r < 4; ++r)
#pragma unroll
            for (int c = 0; c < 4; ++c)
                acc[r][c] = __builtin_amdgcn_mfma_f32_16x16x32_bf16(af[r], bfr[c], acc[r][c], 0, 0, 0);
        __syncthreads();
    }

    float asv[4], adv[4];
#pragma unroll
    for (int c = 0; c < 4; ++c) {
        int col = col_off + c * 16 + lr;
        asv[c] = att_src[col];
        adv[c] = att_dst[col];
    }
    float ps[4][4], pd[4][4];
#pragma unroll
    for (int r = 0; r < 4; ++r)
#pragma unroll
        for (int i = 0; i < 4; ++i) { ps[r][i] = 0.f; pd[r][i] = 0.f; }

#pragma unroll
    for (int c = 0; c < 4; ++c) {
        int col = col_off + c * 16 + lr;
#pragma unroll
        for (int r = 0; r < 4; ++r) {
#pragma unroll
            for (int i = 0; i < 4; ++i) {
                int row = row0 + r * 16 + q * 4 + i;   // < NP by construction
                float v = acc[r][c][i];
                h[(size_t)row * HD + col] = (__bf16)v;
                ps[r][i] += v * asv[c];
                pd[r][i] += v * adv[c];
            }
        }
    }
#pragma unroll
    for (int r = 0; r < 4; ++r)
#pragma unroll
        for (int i = 0; i < 4; ++i) {
#pragma unroll
            for (int m = 1; m < 16; m <<= 1) {
                ps[r][i] += __shfl_xor(ps[r][i], m);
                pd[r][i] += __shfl_xor(pd[r][i], m);
            }
        }
    if (lr == 0) {
#pragma unroll
        for (int r = 0; r < 4; ++r)
#pragma unroll
            for (int i = 0; i < 4; ++i) {
                int row = row0 + r * 16 + q * 4 + i;
                a_s[row * 4 + wv] = ps[r][i];
                a_d[row * 4 + wv] = pd[r][i];
            }
    }
}

__device__ __forceinline__ float lrelu(float v) { return v >= 0.f ? v : NEG_SLOPE * v; }

// ---------------------------------------------------------------------------
// Fused GAT-aggregate + MLP. One block = 64 output rows.
// Phase A: round-1 gather algorithm (1 node per wave iteration, 16 per wave):
//   per-destination softmax over <=64 in-edges (64-lane shuffle reduce),
//   alpha-weighted gather of h rows with 8 sources in flight (bf16x8 loads),
//   result (+b_gat) written bf16 into the 64x256 LDS tile, XOR-swizzled
//   (byte ^= (row&7)<<4) so stage-1 ds_read_b128 A-fragments are at the
//   b128 bank floor (8-way, same as the old As[64][32] layout).
// Phase B: stage1 relu(tile@W1+b1) -> h1 (reuses the SAME 32KB tile, dead
//   after stage-1 reads); stage2 h1@W2; stage3 relu(+b2)@W3+b3 -> out.
// Eliminates the gat_bf global round-trip (25MB W + 25MB R) and one launch,
// and overlaps gather (memory) of some blocks with MFMA of others.
__global__ __launch_bounds__(256) void fused_gat_mlp_kernel(const __bf16* __restrict__ h,
                                                            const float* __restrict__ a_s,
                                                            const float* __restrict__ a_d,
                                                            const int* __restrict__ cnt,
                                                            const unsigned short* __restrict__ bucket,
                                                            const float* __restrict__ b_gat,
                                                            const __bf16* __restrict__ W1t,
                                                            const __bf16* __restrict__ W2t,
                                                            const float* __restrict__ b1,
                                                            const float* __restrict__ b2,
                                                            const float* __restrict__ W3,
                                                            const float* __restrict__ b3,
                                                            float* __restrict__ out) {
    __shared__ __bf16 tile[64 * 256];     // 32 KB: gathered GAT rows, then h1
    __shared__ __bf16 Ws[256 * 32];       // 16 KB
    __shared__ unsigned short s_src[4][64];
    __shared__ float s_alpha[4][64][4];
    __shared__ float s_out[64][2];
    // total 54.3 KB -> 3 blocks/CU

    const int t = threadIdx.x;
    const int lane = t & 63, wv = t >> 6;
    const int row0 = blockIdx.x * 64;

    if (t < 128) ((float*)s_out)[t] = 0.f;

    // ---- phase A: gather (round-1 algorithm, 16 nodes per wave) ----
    {
        const int half = lane >> 5;
        const int l32 = lane & 31;
        const int c0 = l32 * 8;
        const int head = l32 >> 3;
        for (int it = 0; it < 16; ++it) {
            const int row = wv * 16 + it;
            const int n = row0 + row;
            int deg = (n < N_NODES) ? cnt[(size_t)n * CNT_STRIDE] : 0;
            if (deg > CAP) deg = CAP;
            int src = n;
            float4 e = {-1e30f, -1e30f, -1e30f, -1e30f};
            float4 ad = *(const float4*)&a_d[n * 4];
            if (lane < deg) {
                src = bucket[n * CAP + lane];
                float4 as4 = *(const float4*)&a_s[src * 4];
                e.x = lrelu(as4.x + ad.x);
                e.y = lrelu(as4.y + ad.y);
                e.z = lrelu(as4.z + ad.z);
                e.w = lrelu(as4.w + ad.w);
            }
            float4 m = e;
#pragma unroll
            for (int off = 1; off < 64; off <<= 1) {
                m.x = fmaxf(m.x, __shfl_xor(m.x, off));
                m.y = fmaxf(m.y, __shfl_xor(m.y, off));
                m.z = fmaxf(m.z, __shfl_xor(m.z, off));
                m.w = fmaxf(m.w, __shfl_xor(m.w, off));
            }
            float4 wgt = {0, 0, 0, 0};
            if (lane < deg) {
                wgt.x = __expf(e.x - m.x); wgt.y = __expf(e.y - m.y);
                wgt.z = __expf(e.z - m.z); wgt.w = __expf(e.w - m.w);
            }
            float4 s = wgt;
#pragma unroll
            for (int off = 1; off < 64; off <<= 1) {
                s.x += __shfl_xor(s.x, off); s.y += __shfl_xor(s.y, off);
                s.z += __shfl_xor(s.z, off); s.w += __shfl_xor(s.w, off);
            }
            s_src[wv][lane] = (unsigned short)src;
            s_alpha[wv][lane][0] = wgt.x / s.x;
            s_alpha[wv][lane][1] = wgt.y / s.y;
            s_alpha[wv][lane][2] = wgt.z / s.z;
            s_alpha[wv][lane][3] = wgt.w / s.w;
            // wave-private LDS region: enforce W->R ordering without a
            // block barrier.
            asm volatile("s_waitcnt lgkmcnt(0)" ::: "memory");
            __builtin_amdgcn_sched_barrier(0);

            float acc[8];
#pragma unroll
            for (int k = 0; k < 8; ++k) acc[k] = 0.f;

            const int mde = (deg + 1) & ~1;
            int j = 0;
            for (; j + 8 <= mde; j += 8) {     // 8 sources in flight
                int j0 = j + half, j1 = j + 2 + half, j2 = j + 4 + half, j3 = j + 6 + half;
                int s0 = s_src[wv][j0], s1 = s_src[wv][j1];
                int s2 = s_src[wv][j2], s3 = s_src[wv][j3];
                float a0 = s_alpha[wv][j0][head], a1 = s_alpha[wv][j1][head];
                float a2 = s_alpha[wv][j2][head], a3 = s_alpha[wv][j3][head];
                bf16x8 h0 = *(const bf16x8*)&h[(size_t)s0 * HD + c0];
                bf16x8 h1 = *(const bf16x8*)&h[(size_t)s1 * HD + c0];
                bf16x8 h2 = *(const bf16x8*)&h[(size_t)s2 * HD + c0];
                bf16x8 h3 = *(const bf16x8*)&h[(size_t)s3 * HD + c0];
#pragma unroll
                for (int k = 0; k < 8; ++k)
                    acc[k] += a0 * (float)h0[k] + a1 * (float)h1[k]
                            + a2 * (float)h2[k] + a3 * (float)h3[k];
            }
            for (; j < mde; j += 2) {
                int j0 = j + half;
                int s0 = s_src[wv][j0];
                float a0 = s_alpha[wv][j0][head];
                bf16x8 h0 = *(const bf16x8*)&h[(size_t)s0 * HD + c0];
#pragma unroll
                for (int k = 0; k < 8; ++k)
                    acc[k] += a0 * (float)h0[k];
            }
#pragma unroll
            for (int k = 0; k < 8; ++k) acc[k] += __shfl_xor(acc[k], 32);

            if (half == 0) {
                float4 bg0 = *(const float4*)&b_gat[c0];
                float4 bg1 = *(const float4*)&b_gat[c0 + 4];
                bf16x8 o;
                o[0] = (__bf16)(acc[0] + bg0.x); o[1] = (__bf16)(acc[1] + bg0.y);
                o[2] = (__bf16)(acc[2] + bg0.z); o[3] = (__bf16)(acc[3] + bg0.w);
                o[4] = (__bf16)(acc[4] + bg1.x); o[5] = (__bf16)(acc[5] + bg1.y);
                o[6] = (__bf16)(acc[6] + bg1.z); o[7] = (__bf16)(acc[7] + bg1.w);
                const int byte_off = row * 512 + ((l32 * 16) ^ ((row & 7) << 4));
                *(bf16x8*)((char*)tile + byte_off) = o;
            }
        }
    }
    __syncthreads();

    // ---- phase B: fused MLP ----
    const int lr = lane & 15, q = lane >> 4, lk = q * 8;
    const int col_off = wv * 64;
    const int sr = t >> 2, sk = (t & 3) * 8;

    f32x4 acc[4][4];
#pragma unroll
    for (int r = 0; r < 4; ++r)
#pragma unroll
        for (int c = 0; c < 4; ++c) acc[r][c] = f32x4{0.f, 0.f, 0.f, 0.f};

    // stage 1: h1 = relu(tile @ W1 + b1) -> tile (in place, layout change)
    for (int k0 = 0; k0 < HD; k0 += 32) {
#pragma unroll
        for (int s = 0; s < 4; ++s) {
            int r = s * 64 + sr;
            GLD_LDS16(&W1t[(size_t)r * HD + k0 + sk], &Ws[r * 32 + sk]);
        }
        __syncthreads();
        bf16x8 af[4], bfr[4];
#pragma unroll
        for (int i = 0; i < 4; ++i) {
            const int ar = i * 16 + lr;
            const int abyte = ar * 512 + ((k0 * 2 + q * 16) ^ ((ar & 7) << 4));
            af[i]  = *(const bf16x8*)((const char*)tile + abyte);
            bfr[i] = *(const bf16x8*)&Ws[(col_off + i * 16 + lr) * 32 + lk];
        }
#pragma unroll
        for (int r = 0; r < 4; ++r)
#pragma unroll
            for (int c = 0; c < 4; ++c)
                acc[r][c] = __builtin_amdgcn_mfma_f32_16x16x32_bf16(af[r], bfr[c], acc[r][c], 0, 0, 0);
        __syncthreads();
    }
    // gathered tile fully consumed (barrier above) -> overwrite with h1:
    // chunk c holds k in [32c, 32c+32): tile[cb + row*32 + kk]
#pragma unroll
    for (int c = 0; c < 4; ++c) {
        int col = col_off + c * 16 + lr;
        float bv = b1[col];
        int cb = (col >> 5) * 2048;
        int kk = col & 31;
#pragma unroll
        for (int r = 0; r < 4; ++r)
#pragma unroll
            for (int i = 0; i < 4; ++i) {
                int row = r * 16 + q * 4 + i;
                float v = fmaxf(acc[r][c][i] + bv, 0.f);
                tile[cb + row * 32 + kk] = (__bf16)v;
                acc[r][c][i] = 0.f;
            }
    }
    __syncthreads();

    // stage 2: h2 = h1 @ W2
    for (int k0 = 0; k0 < HID; k0 += 32) {
#pragma unroll
        for (int s = 0; s < 4; ++s) {
            int r = s * 64 + sr;
            GLD_LDS16(&W2t[(size_t)r * HID + k0 + sk], &Ws[r * 32 + sk]);
        }
        __syncthreads();
        const int cb = (k0 >> 5) * 2048;
        bf16x8 af[4], bfr[4];
#pragma unroll
        for (int i = 0; i < 4; ++i) {
            af[i]  = *(const bf16x8*)&tile[cb + (i * 16 + lr) * 32 + lk];
            bfr[i] = *(const bf16x8*)&Ws[(col_off + i * 16 + lr) * 32 + lk];
        }
#pragma unroll
        for (int r = 0; r < 4; ++r)
#pragma unroll
            for (int c = 0; c < 4; ++c)
                acc[r][c] = __builtin_amdgcn_mfma_f32_16x16x32_bf16(af[r], bfr[c], acc[r][c], 0, 0, 0);
        __syncthreads();
    }

    // stage 3: out = relu(h2+b2) @ W3 + b3 (fp32 throughout)
    float b2v[4], w30[4], w31[4];
#pragma unroll
    for (int c = 0; c < 4; ++c) {
        int col = col_off + c * 16 + lr;
        b2v[c] = b2[col];
        w30[c] = W3[col * 2];
        w31[c] = W3[col * 2 + 1];
    }
#pragma unroll
    for (int r = 0; r < 4; ++r) {
#pragma unroll
        for (int i = 0; i < 4; ++i) {
            float o0 = 0.f, o1 = 0.f;
#pragma unroll
            for (int c = 0; c < 4; ++c) {
                float v = fmaxf(acc[r][c][i] + b2v[c], 0.f);
                o0 += v * w30[c];
                o1 += v * w31[c];
            }
#pragma unroll
            for (int m = 1; m < 16; m <<= 1) {
                o0 += __shfl_xor(o0, m);
                o1 += __shfl_xor(o1, m);
            }
            if (lr == 0) {
                int row = r * 16 + q * 4 + i;
                atomicAdd(&s_out[row][0], o0);
                atomicAdd(&s_out[row][1], o1);
            }
        }
    }
    __syncthreads();
    if (t < 128) {
        int row = t >> 1, o = t & 1;
        int g = row0 + row;
        if (g < N_NODES) out[g * 2 + o] = s_out[row][o] + b3[o];
    }
}

// ---------------------------------------------------------------------------
extern "C" void kernel_launch(void* const* d_in, const int* in_sizes, int n_in,
                              void* d_out, int out_size, void* d_ws, size_t ws_size,
                              hipStream_t stream) {
    const float* x       = (const float*)d_in[0];
    const int*   ei      = (const int*)d_in[1];
    const float* W_gat   = (const float*)d_in[2];
    const float* att_src = (const float*)d_in[3];
    const float* att_dst = (const float*)d_in[4];
    const float* b_gat   = (const float*)d_in[5];
    const float* W1      = (const float*)d_in[6];
    const float* b1      = (const float*)d_in[7];
    const float* W2      = (const float*)d_in[8];
    const float* b2      = (const float*)d_in[9];
    const float* W3      = (const float*)d_in[10];
    const float* b3      = (const float*)d_in[11];
    float* out = (float*)d_out;

    char* ws = (char*)d_ws;
    __bf16* h_bf   = (__bf16*)ws;  ws += (size_t)NP * HD * 2;
    __bf16* Wg_t   = (__bf16*)ws;  ws += (size_t)HD * F_IN * 2;
    __bf16* W1_t   = (__bf16*)ws;  ws += (size_t)HID * HD * 2;
    __bf16* W2_t   = (__bf16*)ws;  ws += (size_t)HID * HID * 2;
    float* a_s     = (float*)ws;   ws += (size_t)NP * 4 * 4;
    float* a_d     = (float*)ws;   ws += (size_t)NP * 4 * 4;
    int* cnt       = (int*)ws;     ws += (size_t)N_NODES * CNT_STRIDE * 4;
    unsigned short* bucket = (unsigned short*)ws;
    ws += (size_t)N_NODES * CAP * 2;

    prep_kernel<<<PB_INIT + PB_WG + PB_W1 + PB_W2, 256, 0, stream>>>(
        W_gat, W1, W2, Wg_t, W1_t, W2_t, cnt, bucket);
    g1_fill_kernel<<<G1_BLOCKS + FILL_BLOCKS, 256, 0, stream>>>(
        x, Wg_t, att_src, att_dst, ei, h_bf, a_s, a_d, cnt, bucket);
    fused_gat_mlp_kernel<<<NP / 64, 256, 0, stream>>>(h_bf, a_s, a_d, cnt, bucket,
                                                      b_gat, W1_t, W2_t, b1, b2,
                                                      W3, b3, out);
}

// Round 5
// 245.809 us; speedup vs baseline: 1.9934x; 1.1823x over previous
//
#include <hip/hip_runtime.h>
#include <math.h>

#define N_NODES 50000
#define NP 50048          // padded to multiple of 64 for GEMM tiles
#define F_IN 128
#define HD 256            // HEADS*D_HEAD
#define HID 256
#define NE 800000
#define CAP 64
#define NEG_SLOPE 0.2f
#define G1_BLOCKS (NP / 64)       // 782 gemm1 blocks in the combined launch
#define FILL_ILP 8
#define FILL_BLOCKS ((NE + 256 * FILL_ILP - 1) / (256 * FILL_ILP))  // 391
#define CNT_STRIDE 4              // 16B/counter: mild anti-contention

typedef __attribute__((ext_vector_type(8))) __bf16 bf16x8;
typedef __attribute__((ext_vector_type(4))) __bf16 bf16x4;
typedef __attribute__((ext_vector_type(4))) float f32x4;

#define GLD_LDS16(g, l)                                                      \
    __builtin_amdgcn_global_load_lds(                                        \
        (const __attribute__((address_space(1))) unsigned int*)(g),          \
        (__attribute__((address_space(3))) unsigned int*)(l), 16, 0, 0)

// ---------------------------------------------------------------------------
// prep: cnt/bucket init + 3 weight transposes. One launch.
#define PB_INIT 196
#define PB_WG   128
#define PB_W1   256
#define PB_W2   256

__global__ __launch_bounds__(256) void prep_kernel(const float* __restrict__ Wg,
                                                   const float* __restrict__ W1,
                                                   const float* __restrict__ W2,
                                                   __bf16* __restrict__ Wg_t,
                                                   __bf16* __restrict__ W1_t,
                                                   __bf16* __restrict__ W2_t,
                                                   int* __restrict__ cnt,
                                                   unsigned short* __restrict__ bucket) {
    int b = blockIdx.x, t = threadIdx.x;
    if (b < PB_INIT) {
        int n = b * 256 + t;
        if (n < N_NODES) { cnt[(size_t)n * CNT_STRIDE] = 1; bucket[n * CAP] = (unsigned short)n; }
    } else if (b < PB_INIT + PB_WG) {
        int i = (b - PB_INIT) * 256 + t;             // 32768 = HD*F_IN
        int m = i >> 7, k = i & 127;
        Wg_t[i] = (__bf16)Wg[(size_t)k * HD + m];
    } else if (b < PB_INIT + PB_WG + PB_W1) {
        int i = (b - PB_INIT - PB_WG) * 256 + t;     // 65536
        int m = i >> 8, k = i & 255;
        W1_t[i] = (__bf16)W1[(size_t)k * HID + m];
    } else {
        int i = (b - PB_INIT - PB_WG - PB_W1) * 256 + t;
        int m = i >> 8, k = i & 255;
        W2_t[i] = (__bf16)W2[(size_t)k * HID + m];
    }
}

// ---------------------------------------------------------------------------
// Combined launch: blocks [0, G1_BLOCKS) run GEMM1 (x @ W_gat, fused fp32->
// bf16 convert + attention coefficients); blocks [G1_BLOCKS, +FILL_BLOCKS)
// run the edge-bucket fill (8 edges/thread for 8 independent atomic chains —
// the atomic return-latency chain is concurrency-bound at this kernel's
// VGPR-capped occupancy, so more in-flight atomics per lane is the lever).
__global__ __launch_bounds__(256) void g1_fill_kernel(const float* __restrict__ x,
                                                      const __bf16* __restrict__ Bt,
                                                      const float* __restrict__ att_src,
                                                      const float* __restrict__ att_dst,
                                                      const int* __restrict__ ew,
                                                      __bf16* __restrict__ h,
                                                      float* __restrict__ a_s,
                                                      float* __restrict__ a_d,
                                                      int* __restrict__ cnt,
                                                      unsigned short* __restrict__ bucket) {
    __shared__ __bf16 As[64 * 32];    // [row][k]
    __shared__ __bf16 Bs[256 * 32];   // [col][k]

    if (blockIdx.x >= G1_BLOCKS) {
        // ---- fill branch, ILP-8: int64-vs-int32 detection via per-wave
        // ballot of high words (int64 => all high words zero). u16 bucket.
        const int base = (blockIdx.x - G1_BLOCKS) * (256 * FILL_ILP) + threadIdx.x;
        long long p[FILL_ILP];
        bool v[FILL_ILP];
        int s[FILL_ILP], d[FILL_ILP], pos[FILL_ILP];
        int hiall = 0;
#pragma unroll
        for (int k = 0; k < FILL_ILP; ++k) {
            const int e = base + k * 256;
            v[k] = e < NE;
            p[k] = 0;
            if (v[k]) p[k] = *(const long long*)&ew[2 * e];
            hiall |= (int)(p[k] >> 32);
        }
        unsigned long long bal = __ballot(hiall != 0);
        if (bal == 0) {   // int64 layout: pair (lo,hi) per value
#pragma unroll
            for (int k = 0; k < FILL_ILP; ++k) {
                const int e = base + k * 256;
                s[k] = (int)p[k];
                d[k] = 0;
                if (v[k]) d[k] = ew[2 * NE + 2 * e];
            }
        } else {          // int32 layout
#pragma unroll
            for (int k = 0; k < FILL_ILP; ++k) {
                const int e = base + k * 256;
                s[k] = 0; d[k] = 0;
                if (v[k]) { s[k] = ew[e]; d[k] = ew[NE + e]; }
            }
        }
#pragma unroll
        for (int k = 0; k < FILL_ILP; ++k) {
            pos[k] = CAP;
            if (v[k]) pos[k] = atomicAdd(&cnt[(size_t)d[k] * CNT_STRIDE], 1);
        }
#pragma unroll
        for (int k = 0; k < FILL_ILP; ++k)
            if (pos[k] < CAP) bucket[d[k] * CAP + pos[k]] = (unsigned short)s[k];
        return;
    }

    // ---- GEMM1 branch: tile 64 rows x 256 cols, 4 waves (col_off = head*64)
    const int t = threadIdx.x;
    const int lane = t & 63, wv = t >> 6;
    const int lr = lane & 15, q = lane >> 4, lk = q * 8;
    const int col_off = wv * 64;
    const int row0 = blockIdx.x * 64;
    const int sr = t >> 2, sk = (t & 3) * 8;
    const int arow = row0 + sr;
    const bool avalid = arow < N_NODES;

    f32x4 acc[4][4];
#pragma unroll
    for (int r = 0; r < 4; ++r)
#pragma unroll
        for (int c = 0; c < 4; ++c) acc[r][c] = f32x4{0.f, 0.f, 0.f, 0.f};

    for (int k0 = 0; k0 < F_IN; k0 += 32) {
        // A staging: load x fp32, convert to bf16, ds_write (fused convert)
        float4 v0 = {0, 0, 0, 0}, v1 = {0, 0, 0, 0};
        if (avalid) {
            const float* xp = &x[(size_t)arow * F_IN + k0 + sk];
            v0 = *(const float4*)xp;
            v1 = *(const float4*)(xp + 4);
        }
        bf16x8 o;
        o[0] = (__bf16)v0.x; o[1] = (__bf16)v0.y; o[2] = (__bf16)v0.z; o[3] = (__bf16)v0.w;
        o[4] = (__bf16)v1.x; o[5] = (__bf16)v1.y; o[6] = (__bf16)v1.z; o[7] = (__bf16)v1.w;
        *(bf16x8*)&As[sr * 32 + sk] = o;
        // B staging: async global->LDS
#pragma unroll
        for (int s = 0; s < 4; ++s) {
            int r = s * 64 + sr;
            GLD_LDS16(&Bt[(size_t)r * F_IN + k0 + sk], &Bs[r * 32 + sk]);
        }
        __syncthreads();
        bf16x8 af[4], bfr[4];
#pragma unroll
        for (int i = 0; i < 4; ++i) {
            af[i]  = *(const bf16x8*)&As[(i * 16 + lr) * 32 + lk];
            bfr[i] = *(const bf16x8*)&Bs[(col_off + i * 16 + lr) * 32 + lk];
        }
#pragma unroll
        for (int r = 0; r < 4; ++r)
#pragma unroll
            for (int c = 0; c < 4; ++c)
                acc[r][c] = __builtin_amdgcn_mfma_f32_16x16x32_bf16(af[r], bfr[c], acc[r][c], 0, 0, 0);
        __syncthreads();
    }

    float asv[4], adv[4];
#pragma unroll
    for (int c = 0; c < 4; ++c) {
        int col = col_off + c * 16 + lr;
        asv[c] = att_src[col];
        adv[c] = att_dst[col];
    }
    float ps[4][4], pd[4][4];
#pragma unroll
    for (int r = 0; r < 4; ++r)
#pragma unroll
        for (int i = 0; i < 4; ++i) { ps[r][i] = 0.f; pd[r][i] = 0.f; }

#pragma unroll
    for (int c = 0; c < 4; ++c) {
        int col = col_off + c * 16 + lr;
#pragma unroll
        for (int r = 0; r < 4; ++r) {
#pragma unroll
            for (int i = 0; i < 4; ++i) {
                int row = row0 + r * 16 + q * 4 + i;   // < NP by construction
                float v = acc[r][c][i];
                h[(size_t)row * HD + col] = (__bf16)v;
                ps[r][i] += v * asv[c];
                pd[r][i] += v * adv[c];
            }
        }
    }
#pragma unroll
    for (int r = 0; r < 4; ++r)
#pragma unroll
        for (int i = 0; i < 4; ++i) {
#pragma unroll
            for (int m = 1; m < 16; m <<= 1) {
                ps[r][i] += __shfl_xor(ps[r][i], m);
                pd[r][i] += __shfl_xor(pd[r][i], m);
            }
        }
    if (lr == 0) {
#pragma unroll
        for (int r = 0; r < 4; ++r)
#pragma unroll
            for (int i = 0; i < 4; ++i) {
                int row = row0 + r * 16 + q * 4 + i;
                a_s[row * 4 + wv] = ps[r][i];
                a_d[row * 4 + wv] = pd[r][i];
            }
    }
}

__device__ __forceinline__ float lrelu(float v) { return v >= 0.f ? v : NEG_SLOPE * v; }

// ---------------------------------------------------------------------------
// Fused per-destination softmax + weighted gather-aggregate (round-1 proven
// structure: ONE WAVE PER BLOCK, grid = N_NODES) + latency fix: the first 8
// h-row loads depend only on bucket (not on alpha), so they are issued via
// __shfl(src, j) broadcasts BEFORE the softmax. Load order is a_s first,
// then the h prefetch, so the in-order vmcnt lets softmax proceed while the
// prefetched rows are still in flight.
__global__ __launch_bounds__(64) void gat_aggregate_kernel(const __bf16* __restrict__ h,
                                                           const float* __restrict__ a_s,
                                                           const float* __restrict__ a_d,
                                                           const int* __restrict__ cnt,
                                                           const unsigned short* __restrict__ bucket,
                                                           const float* __restrict__ b_gat,
                                                           __bf16* __restrict__ gat) {
    __shared__ unsigned short s_src[64];
    __shared__ float s_alpha[64][4];
    const int lane = threadIdx.x;
    const int n = blockIdx.x;          // grid is exactly N_NODES

    int deg = cnt[(size_t)n * CNT_STRIDE];
    if (deg > CAP) deg = CAP;
    int src = n;                       // self for invalid lanes (alpha=0)
    float4 ad = *(const float4*)&a_d[n * 4];
    float4 as4 = {0, 0, 0, 0};
    if (lane < deg) {
        src = bucket[n * CAP + lane];
        as4 = *(const float4*)&a_s[src * 4];   // issue BEFORE h prefetch
    }

    // ---- prefetch first gather burst (8 rows; addresses from shfl of src).
    // Invalid lanes hold src=n -> addresses always in range; alpha zeroes
    // their contribution later.
    const int half = lane >> 5;
    const int l32 = lane & 31;
    const int c0 = l32 * 8;
    const int head = l32 >> 3;
    const int pj0 = __shfl(src, half);
    const int pj1 = __shfl(src, 2 + half);
    const int pj2 = __shfl(src, 4 + half);
    const int pj3 = __shfl(src, 6 + half);
    const bf16x8 hp0 = *(const bf16x8*)&h[(size_t)pj0 * HD + c0];
    const bf16x8 hp1 = *(const bf16x8*)&h[(size_t)pj1 * HD + c0];
    const bf16x8 hp2 = *(const bf16x8*)&h[(size_t)pj2 * HD + c0];
    const bf16x8 hp3 = *(const bf16x8*)&h[(size_t)pj3 * HD + c0];

    // ---- softmax (overlaps the in-flight prefetch)
    float4 e = {-1e30f, -1e30f, -1e30f, -1e30f};
    if (lane < deg) {
        e.x = lrelu(as4.x + ad.x);
        e.y = lrelu(as4.y + ad.y);
        e.z = lrelu(as4.z + ad.z);
        e.w = lrelu(as4.w + ad.w);
    }
    float4 m = e;
#pragma unroll
    for (int off = 1; off < 64; off <<= 1) {
        m.x = fmaxf(m.x, __shfl_xor(m.x, off));
        m.y = fmaxf(m.y, __shfl_xor(m.y, off));
        m.z = fmaxf(m.z, __shfl_xor(m.z, off));
        m.w = fmaxf(m.w, __shfl_xor(m.w, off));
    }
    float4 wgt = {0, 0, 0, 0};
    if (lane < deg) {
        wgt.x = __expf(e.x - m.x); wgt.y = __expf(e.y - m.y);
        wgt.z = __expf(e.z - m.z); wgt.w = __expf(e.w - m.w);
    }
    float4 s = wgt;
#pragma unroll
    for (int off = 1; off < 64; off <<= 1) {
        s.x += __shfl_xor(s.x, off); s.y += __shfl_xor(s.y, off);
        s.z += __shfl_xor(s.z, off); s.w += __shfl_xor(s.w, off);
    }
    s_src[lane] = (unsigned short)src;
    s_alpha[lane][0] = wgt.x / s.x;
    s_alpha[lane][1] = wgt.y / s.y;
    s_alpha[lane][2] = wgt.z / s.z;
    s_alpha[lane][3] = wgt.w / s.w;
    __syncthreads();                   // single-wave: waitcnt + cheap barrier

    float acc[8];
#pragma unroll
    for (int k = 0; k < 8; ++k) acc[k] = 0.f;

    const int mde = (deg + 1) & ~1;
    int j = 0;
    if (mde >= 8) {                    // consume the prefetched burst
        const float a0 = s_alpha[half][head];
        const float a1 = s_alpha[2 + half][head];
        const float a2 = s_alpha[4 + half][head];
        const float a3 = s_alpha[6 + half][head];
#pragma unroll
        for (int k = 0; k < 8; ++k)
            acc[k] += a0 * (float)hp0[k] + a1 * (float)hp1[k]
                    + a2 * (float)hp2[k] + a3 * (float)hp3[k];
        j = 8;
        for (; j + 8 <= mde; j += 8) {   // 8 sources in flight (4 loads/half)
            int j0 = j + half, j1 = j + 2 + half, j2 = j + 4 + half, j3 = j + 6 + half;
            int s0 = s_src[j0], s1 = s_src[j1], s2 = s_src[j2], s3 = s_src[j3];
            float b0 = s_alpha[j0][head], b1 = s_alpha[j1][head];
            float b2 = s_alpha[j2][head], b3 = s_alpha[j3][head];
            bf16x8 h0 = *(const bf16x8*)&h[(size_t)s0 * HD + c0];
            bf16x8 h1 = *(const bf16x8*)&h[(size_t)s1 * HD + c0];
            bf16x8 h2 = *(const bf16x8*)&h[(size_t)s2 * HD + c0];
            bf16x8 h3 = *(const bf16x8*)&h[(size_t)s3 * HD + c0];
#pragma unroll
            for (int k = 0; k < 8; ++k)
                acc[k] += b0 * (float)h0[k] + b1 * (float)h1[k]
                        + b2 * (float)h2[k] + b3 * (float)h3[k];
        }
    }
    for (; j < mde; j += 2) {
        int j0 = j + half;
        int s0 = s_src[j0];
        float a0 = s_alpha[j0][head];
        bf16x8 h0 = *(const bf16x8*)&h[(size_t)s0 * HD + c0];
#pragma unroll
        for (int k = 0; k < 8; ++k)
            acc[k] += a0 * (float)h0[k];
    }
    // combine the two halves
#pragma unroll
    for (int k = 0; k < 8; ++k) acc[k] += __shfl_xor(acc[k], 32);

    if (half == 0) {
        float4 bg0 = *(const float4*)&b_gat[c0];
        float4 bg1 = *(const float4*)&b_gat[c0 + 4];
        bf16x8 o;
        o[0] = (__bf16)(acc[0] + bg0.x); o[1] = (__bf16)(acc[1] + bg0.y);
        o[2] = (__bf16)(acc[2] + bg0.z); o[3] = (__bf16)(acc[3] + bg0.w);
        o[4] = (__bf16)(acc[4] + bg1.x); o[5] = (__bf16)(acc[5] + bg1.y);
        o[6] = (__bf16)(acc[6] + bg1.z); o[7] = (__bf16)(acc[7] + bg1.w);
        *(bf16x8*)&gat[(size_t)n * HD + c0] = o;
    }
}

// ---------------------------------------------------------------------------
// Fused MLP: out = relu(relu(gat@W1+b1)@W2+b2)@W3 + b3, one kernel.
__global__ __launch_bounds__(256) void fused_mlp_kernel(const __bf16* __restrict__ A,
                                                        const __bf16* __restrict__ W1t,
                                                        const __bf16* __restrict__ W2t,
                                                        const float* __restrict__ b1,
                                                        const float* __restrict__ b2,
                                                        const float* __restrict__ W3,
                                                        const float* __restrict__ b3,
                                                        float* __restrict__ out) {
    __shared__ __bf16 As[64 * 32];        // 4 KB
    __shared__ __bf16 Ws[256 * 32];       // 16 KB
    __shared__ __bf16 h1s[8 * 64 * 32];   // 32 KB, chunk c holds k in [32c,32c+32)
    __shared__ float s_out[64][2];
    const int t = threadIdx.x;
    const int lane = t & 63, wv = t >> 6;
    const int lr = lane & 15, q = lane >> 4, lk = q * 8;
    const int col_off = wv * 64;
    const int row0 = blockIdx.x * 64;
    const int sr = t >> 2, sk = (t & 3) * 8;

    if (t < 128) ((float*)s_out)[t] = 0.f;

    f32x4 acc[4][4];
#pragma unroll
    for (int r = 0; r < 4; ++r)
#pragma unroll
        for (int c = 0; c < 4; ++c) acc[r][c] = f32x4{0.f, 0.f, 0.f, 0.f};

    // ---- stage 1: h1 = relu(gat @ W1 + b1) -> LDS
    for (int k0 = 0; k0 < HD; k0 += 32) {
        GLD_LDS16(&A[(size_t)(row0 + sr) * HD + k0 + sk], &As[sr * 32 + sk]);
#pragma unroll
        for (int s = 0; s < 4; ++s) {
            int r = s * 64 + sr;
            GLD_LDS16(&W1t[(size_t)r * HD + k0 + sk], &Ws[r * 32 + sk]);
        }
        __syncthreads();
        bf16x8 af[4], bfr[4];
#pragma unroll
        for (int i = 0; i < 4; ++i) {
            af[i]  = *(const bf16x8*)&As[(i * 16 + lr) * 32 + lk];
            bfr[i] = *(const bf16x8*)&Ws[(col_off + i * 16 + lr) * 32 + lk];
        }
#pragma unroll
        for (int r = 0; r < 4; ++r)
#pragma unroll
            for (int c = 0; c < 4; ++c)
                acc[r][c] = __builtin_amdgcn_mfma_f32_16x16x32_bf16(af[r], bfr[c], acc[r][c], 0, 0, 0);
        __syncthreads();
    }
#pragma unroll
    for (int c = 0; c < 4; ++c) {
        int col = col_off + c * 16 + lr;
        float bv = b1[col];
        int cb = (col >> 5) * 2048;
        int kk = col & 31;
#pragma unroll
        for (int r = 0; r < 4; ++r)
#pragma unroll
            for (int i = 0; i < 4; ++i) {
                int row = r * 16 + q * 4 + i;
                float v = fmaxf(acc[r][c][i] + bv, 0.f);
                h1s[cb + row * 32 + kk] = (__bf16)v;
                acc[r][c][i] = 0.f;
            }
    }
    __syncthreads();

    // ---- stage 2: h2 = h1 @ W2
    for (int k0 = 0; k0 < HID; k0 += 32) {
#pragma unroll
        for (int s = 0; s < 4; ++s) {
            int r = s * 64 + sr;
            GLD_LDS16(&W2t[(size_t)r * HID + k0 + sk], &Ws[r * 32 + sk]);
        }
        __syncthreads();
        const int cb = (k0 >> 5) * 2048;
        bf16x8 af[4], bfr[4];
#pragma unroll
        for (int i = 0; i < 4; ++i) {
            af[i]  = *(const bf16x8*)&h1s[cb + (i * 16 + lr) * 32 + lk];
            bfr[i] = *(const bf16x8*)&Ws[(col_off + i * 16 + lr) * 32 + lk];
        }
#pragma unroll
        for (int r = 0; r < 4; ++r)
#pragma unroll
            for (int c = 0; c < 4; ++c)
                acc[r][c] = __builtin_amdgcn_mfma_f32_16x16x32_bf16(af[r], bfr[c], acc[r][c], 0, 0, 0);
        __syncthreads();
    }

    // ---- stage 3: out = relu(h2+b2) @ W3 + b3 (fp32 throughout)
    float b2v[4], w30[4], w31[4];
#pragma unroll
    for (int c = 0; c < 4; ++c) {
        int col = col_off + c * 16 + lr;
        b2v[c] = b2[col];
        w30[c] = W3[col * 2];
        w31[c] = W3[col * 2 + 1];
    }
#pragma unroll
    for (int r = 0; r < 4; ++r) {
#pragma unroll
        for (int i = 0; i < 4; ++i) {
            float o0 = 0.f, o1 = 0.f;
#pragma unroll
            for (int c = 0; c < 4; ++c) {
                float v = fmaxf(acc[r][c][i] + b2v[c], 0.f);
                o0 += v * w30[c];
                o1 += v * w31[c];
            }
#pragma unroll
            for (int m = 1; m < 16; m <<= 1) {
                o0 += __shfl_xor(o0, m);
                o1 += __shfl_xor(o1, m);
            }
            if (lr == 0) {
                int row = r * 16 + q * 4 + i;
                atomicAdd(&s_out[row][0], o0);
                atomicAdd(&s_out[row][1], o1);
            }
        }
    }
    __syncthreads();
    if (t < 128) {
        int row = t >> 1, o = t & 1;
        int g = row0 + row;
        if (g < N_NODES) out[g * 2 + o] = s_out[row][o] + b3[o];
    }
}

// ---------------------------------------------------------------------------
extern "C" void kernel_launch(void* const* d_in, const int* in_sizes, int n_in,
                              void* d_out, int out_size, void* d_ws, size_t ws_size,
                              hipStream_t stream) {
    const float* x       = (const float*)d_in[0];
    const int*   ei      = (const int*)d_in[1];
    const float* W_gat   = (const float*)d_in[2];
    const float* att_src = (const float*)d_in[3];
    const float* att_dst = (const float*)d_in[4];
    const float* b_gat   = (const float*)d_in[5];
    const float* W1      = (const float*)d_in[6];
    const float* b1      = (const float*)d_in[7];
    const float* W2      = (const float*)d_in[8];
    const float* b2      = (const float*)d_in[9];
    const float* W3      = (const float*)d_in[10];
    const float* b3      = (const float*)d_in[11];
    float* out = (float*)d_out;

    char* ws = (char*)d_ws;
    __bf16* h_bf   = (__bf16*)ws;  ws += (size_t)NP * HD * 2;
    __bf16* gat_bf = (__bf16*)ws;  ws += (size_t)NP * HD * 2;
    __bf16* Wg_t   = (__bf16*)ws;  ws += (size_t)HD * F_IN * 2;
    __bf16* W1_t   = (__bf16*)ws;  ws += (size_t)HID * HD * 2;
    __bf16* W2_t   = (__bf16*)ws;  ws += (size_t)HID * HID * 2;
    float* a_s     = (float*)ws;   ws += (size_t)NP * 4 * 4;
    float* a_d     = (float*)ws;   ws += (size_t)NP * 4 * 4;
    int* cnt       = (int*)ws;     ws += (size_t)N_NODES * CNT_STRIDE * 4;
    unsigned short* bucket = (unsigned short*)ws;
    ws += (size_t)N_NODES * CAP * 2;

    prep_kernel<<<PB_INIT + PB_WG + PB_W1 + PB_W2, 256, 0, stream>>>(
        W_gat, W1, W2, Wg_t, W1_t, W2_t, cnt, bucket);
    g1_fill_kernel<<<G1_BLOCKS + FILL_BLOCKS, 256, 0, stream>>>(
        x, Wg_t, att_src, att_dst, ei, h_bf, a_s, a_d, cnt, bucket);
    gat_aggregate_kernel<<<N_NODES, 64, 0, stream>>>(h_bf, a_s, a_d, cnt, bucket,
                                                     b_gat, gat_bf);
    fused_mlp_kernel<<<NP / 64, 256, 0, stream>>>(gat_bf, W1_t, W2_t, b1, b2, W3, b3, out);
}

// Round 6
// 242.729 us; speedup vs baseline: 2.0187x; 1.0127x over previous
//
#include <hip/hip_runtime.h>
#include <math.h>

#define N_NODES 50000
#define NP 50048          // padded to multiple of 64 for GEMM tiles
#define F_IN 128
#define HD 256            // HEADS*D_HEAD
#define HID 256
#define NE 800000
#define CAP 64
#define NEG_SLOPE 0.2f
#define G1_BLOCKS (NP / 64)       // 782 gemm1 blocks in the combined launch
#define FILL_BLOCKS ((NE + 1023) / 1024)   // 782 fill blocks, 4 edges/thread
#define CNT_STRIDE 16             // one counter per 64B: kills same-line atomic
                                  // serialization (empirical best, round 1)

typedef __attribute__((ext_vector_type(8))) __bf16 bf16x8;
typedef __attribute__((ext_vector_type(4))) __bf16 bf16x4;
typedef __attribute__((ext_vector_type(4))) float f32x4;

#define GLD_LDS16(g, l)                                                      \
    __builtin_amdgcn_global_load_lds(                                        \
        (const __attribute__((address_space(1))) unsigned int*)(g),          \
        (__attribute__((address_space(3))) unsigned int*)(l), 16, 0, 0)

// write-through 2B store (sc0 sc1): merges at MALL, no per-XCD L2 dirty line.
// Bucket rows are 1 line/node touched by ~16 random CUs -> cached stores
// caused ~37MB of eviction writeback amplification (round-5 WRITE_SIZE).
__device__ __forceinline__ void store_u16_wt(unsigned short* p, unsigned v) {
    unsigned long long a = (unsigned long long)p;
    asm volatile("global_store_short %0, %1, off sc0 sc1" :: "v"(a), "v"(v) : "memory");
}

// ---------------------------------------------------------------------------
// prep: cnt/bucket init + 3 weight transposes. One launch.
#define PB_INIT 196
#define PB_WG   128
#define PB_W1   256
#define PB_W2   256

__global__ __launch_bounds__(256) void prep_kernel(const float* __restrict__ Wg,
                                                   const float* __restrict__ W1,
                                                   const float* __restrict__ W2,
                                                   __bf16* __restrict__ Wg_t,
                                                   __bf16* __restrict__ W1_t,
                                                   __bf16* __restrict__ W2_t,
                                                   int* __restrict__ cnt,
                                                   unsigned short* __restrict__ bucket) {
    int b = blockIdx.x, t = threadIdx.x;
    if (b < PB_INIT) {
        int n = b * 256 + t;
        if (n < N_NODES) { cnt[(size_t)n * CNT_STRIDE] = 1; bucket[n * CAP] = (unsigned short)n; }
    } else if (b < PB_INIT + PB_WG) {
        int i = (b - PB_INIT) * 256 + t;             // 32768 = HD*F_IN
        int m = i >> 7, k = i & 127;
        Wg_t[i] = (__bf16)Wg[(size_t)k * HD + m];
    } else if (b < PB_INIT + PB_WG + PB_W1) {
        int i = (b - PB_INIT - PB_WG) * 256 + t;     // 65536
        int m = i >> 8, k = i & 255;
        W1_t[i] = (__bf16)W1[(size_t)k * HID + m];
    } else {
        int i = (b - PB_INIT - PB_WG - PB_W1) * 256 + t;
        int m = i >> 8, k = i & 255;
        W2_t[i] = (__bf16)W2[(size_t)k * HID + m];
    }
}

// ---------------------------------------------------------------------------
// Combined launch: blocks [0, G1_BLOCKS) run GEMM1 (x @ W_gat, fused fp32->
// bf16 convert + attention coefficients); blocks [G1_BLOCKS, +FILL_BLOCKS)
// run the edge-bucket fill (4 edges/thread — empirical optimum; 8 regressed).
__global__ __launch_bounds__(256) void g1_fill_kernel(const float* __restrict__ x,
                                                      const __bf16* __restrict__ Bt,
                                                      const float* __restrict__ att_src,
                                                      const float* __restrict__ att_dst,
                                                      const int* __restrict__ ew,
                                                      __bf16* __restrict__ h,
                                                      float* __restrict__ a_s,
                                                      float* __restrict__ a_d,
                                                      int* __restrict__ cnt,
                                                      unsigned short* __restrict__ bucket) {
    __shared__ __bf16 As[64 * 32];    // [row][k]
    __shared__ __bf16 Bs[256 * 32];   // [col][k]

    if (blockIdx.x >= G1_BLOCKS) {
        // ---- fill branch, ILP-4: int64-vs-int32 detection via per-wave
        // ballot of high words (int64 => all high words zero). u16 bucket.
        const int base = (blockIdx.x - G1_BLOCKS) * 1024 + threadIdx.x;
        const int e0 = base, e1 = base + 256, e2 = base + 512, e3 = base + 768;
        const bool v0 = e0 < NE, v1 = e1 < NE, v2 = e2 < NE, v3 = e3 < NE;
        long long p0 = 0, p1 = 0, p2 = 0, p3 = 0;
        if (v0) p0 = *(const long long*)&ew[2 * e0];
        if (v1) p1 = *(const long long*)&ew[2 * e1];
        if (v2) p2 = *(const long long*)&ew[2 * e2];
        if (v3) p3 = *(const long long*)&ew[2 * e3];
        const int hiall = (int)(p0 >> 32) | (int)(p1 >> 32) |
                          (int)(p2 >> 32) | (int)(p3 >> 32);
        unsigned long long bal = __ballot(hiall != 0);
        int s0 = 0, s1 = 0, s2 = 0, s3 = 0, d0 = 0, d1 = 0, d2 = 0, d3 = 0;
        if (bal == 0) {   // int64 layout: pair (lo,hi) per value
            s0 = (int)p0; s1 = (int)p1; s2 = (int)p2; s3 = (int)p3;
            if (v0) d0 = ew[2 * NE + 2 * e0];
            if (v1) d1 = ew[2 * NE + 2 * e1];
            if (v2) d2 = ew[2 * NE + 2 * e2];
            if (v3) d3 = ew[2 * NE + 2 * e3];
        } else {          // int32 layout
            if (v0) { s0 = ew[e0]; d0 = ew[NE + e0]; }
            if (v1) { s1 = ew[e1]; d1 = ew[NE + e1]; }
            if (v2) { s2 = ew[e2]; d2 = ew[NE + e2]; }
            if (v3) { s3 = ew[e3]; d3 = ew[NE + e3]; }
        }
        int pos0 = CAP, pos1 = CAP, pos2 = CAP, pos3 = CAP;
        if (v0) pos0 = atomicAdd(&cnt[(size_t)d0 * CNT_STRIDE], 1);
        if (v1) pos1 = atomicAdd(&cnt[(size_t)d1 * CNT_STRIDE], 1);
        if (v2) pos2 = atomicAdd(&cnt[(size_t)d2 * CNT_STRIDE], 1);
        if (v3) pos3 = atomicAdd(&cnt[(size_t)d3 * CNT_STRIDE], 1);
        if (pos0 < CAP) store_u16_wt(&bucket[d0 * CAP + pos0], (unsigned)(unsigned short)s0);
        if (pos1 < CAP) store_u16_wt(&bucket[d1 * CAP + pos1], (unsigned)(unsigned short)s1);
        if (pos2 < CAP) store_u16_wt(&bucket[d2 * CAP + pos2], (unsigned)(unsigned short)s2);
        if (pos3 < CAP) store_u16_wt(&bucket[d3 * CAP + pos3], (unsigned)(unsigned short)s3);
        return;
    }

    // ---- GEMM1 branch: tile 64 rows x 256 cols, 4 waves (col_off = head*64)
    const int t = threadIdx.x;
    const int lane = t & 63, wv = t >> 6;
    const int lr = lane & 15, q = lane >> 4, lk = q * 8;
    const int col_off = wv * 64;
    const int row0 = blockIdx.x * 64;
    const int sr = t >> 2, sk = (t & 3) * 8;
    const int arow = row0 + sr;
    const bool avalid = arow < N_NODES;

    f32x4 acc[4][4];
#pragma unroll
    for (int r = 0; r < 4; ++r)
#pragma unroll
        for (int c = 0; c < 4; ++c) acc[r][c] = f32x4{0.f, 0.f, 0.f, 0.f};

    for (int k0 = 0; k0 < F_IN; k0 += 32) {
        // A staging: load x fp32, convert to bf16, ds_write (fused convert)
        float4 v0 = {0, 0, 0, 0}, v1 = {0, 0, 0, 0};
        if (avalid) {
            const float* xp = &x[(size_t)arow * F_IN + k0 + sk];
            v0 = *(const float4*)xp;
            v1 = *(const float4*)(xp + 4);
        }
        bf16x8 o;
        o[0] = (__bf16)v0.x; o[1] = (__bf16)v0.y; o[2] = (__bf16)v0.z; o[3] = (__bf16)v0.w;
        o[4] = (__bf16)v1.x; o[5] = (__bf16)v1.y; o[6] = (__bf16)v1.z; o[7] = (__bf16)v1.w;
        *(bf16x8*)&As[sr * 32 + sk] = o;
        // B staging: async global->LDS
#pragma unroll
        for (int s = 0; s < 4; ++s) {
            int r = s * 64 + sr;
            GLD_LDS16(&Bt[(size_t)r * F_IN + k0 + sk], &Bs[r * 32 + sk]);
        }
        __syncthreads();
        bf16x8 af[4], bfr[4];
#pragma unroll
        for (int i = 0; i < 4; ++i) {
            af[i]  = *(const bf16x8*)&As[(i * 16 + lr) * 32 + lk];
            bfr[i] = *(const bf16x8*)&Bs[(col_off + i * 16 + lr) * 32 + lk];
        }
#pragma unroll
        for (int r = 0; r < 4; ++r)
#pragma unroll
            for (int c = 0; c < 4; ++c)
                acc[r][c] = __builtin_amdgcn_mfma_f32_16x16x32_bf16(af[r], bfr[c], acc[r][c], 0, 0, 0);
        __syncthreads();
    }

    float asv[4], adv[4];
#pragma unroll
    for (int c = 0; c < 4; ++c) {
        int col = col_off + c * 16 + lr;
        asv[c] = att_src[col];
        adv[c] = att_dst[col];
    }
    float ps[4][4], pd[4][4];
#pragma unroll
    for (int r = 0; r < 4; ++r)
#pragma unroll
        for (int i = 0; i < 4; ++i) { ps[r][i] = 0.f; pd[r][i] = 0.f; }

#pragma unroll
    for (int c = 0; c < 4; ++c) {
        int col = col_off + c * 16 + lr;
#pragma unroll
        for (int r = 0; r < 4; ++r) {
#pragma unroll
            for (int i = 0; i < 4; ++i) {
                int row = row0 + r * 16 + q * 4 + i;   // < NP by construction
                float v = acc[r][c][i];
                h[(size_t)row * HD + col] = (__bf16)v;
                ps[r][i] += v * asv[c];
                pd[r][i] += v * adv[c];
            }
        }
    }
#pragma unroll
    for (int r = 0; r < 4; ++r)
#pragma unroll
        for (int i = 0; i < 4; ++i) {
#pragma unroll
            for (int m = 1; m < 16; m <<= 1) {
                ps[r][i] += __shfl_xor(ps[r][i], m);
                pd[r][i] += __shfl_xor(pd[r][i], m);
            }
        }
    if (lr == 0) {
#pragma unroll
        for (int r = 0; r < 4; ++r)
#pragma unroll
            for (int i = 0; i < 4; ++i) {
                int row = row0 + r * 16 + q * 4 + i;
                a_s[row * 4 + wv] = ps[r][i];
                a_d[row * 4 + wv] = pd[r][i];
            }
    }
}

__device__ __forceinline__ float lrelu(float v) { return v >= 0.f ? v : NEG_SLOPE * v; }

// ---------------------------------------------------------------------------
// Fused per-destination softmax + weighted gather-aggregate (round-1 proven
// structure: ONE WAVE PER BLOCK, grid = N_NODES) + prefetch: the first 8
// h-row loads depend only on bucket (not on alpha), so they are issued via
// __shfl(src, j) broadcasts BEFORE the softmax.
__global__ __launch_bounds__(64) void gat_aggregate_kernel(const __bf16* __restrict__ h,
                                                           const float* __restrict__ a_s,
                                                           const float* __restrict__ a_d,
                                                           const int* __restrict__ cnt,
                                                           const unsigned short* __restrict__ bucket,
                                                           const float* __restrict__ b_gat,
                                                           __bf16* __restrict__ gat) {
    __shared__ unsigned short s_src[64];
    __shared__ float s_alpha[64][4];
    const int lane = threadIdx.x;
    const int n = blockIdx.x;          // grid is exactly N_NODES

    int deg = cnt[(size_t)n * CNT_STRIDE];
    if (deg > CAP) deg = CAP;
    int src = n;                       // self for invalid lanes (alpha=0)
    float4 ad = *(const float4*)&a_d[n * 4];
    float4 as4 = {0, 0, 0, 0};
    if (lane < deg) {
        src = bucket[n * CAP + lane];
        as4 = *(const float4*)&a_s[src * 4];   // issue BEFORE h prefetch
    }

    // ---- prefetch first gather burst (8 rows; addresses from shfl of src).
    const int half = lane >> 5;
    const int l32 = lane & 31;
    const int c0 = l32 * 8;
    const int head = l32 >> 3;
    const int pj0 = __shfl(src, half);
    const int pj1 = __shfl(src, 2 + half);
    const int pj2 = __shfl(src, 4 + half);
    const int pj3 = __shfl(src, 6 + half);
    const bf16x8 hp0 = *(const bf16x8*)&h[(size_t)pj0 * HD + c0];
    const bf16x8 hp1 = *(const bf16x8*)&h[(size_t)pj1 * HD + c0];
    const bf16x8 hp2 = *(const bf16x8*)&h[(size_t)pj2 * HD + c0];
    const bf16x8 hp3 = *(const bf16x8*)&h[(size_t)pj3 * HD + c0];

    // ---- softmax (overlaps the in-flight prefetch)
    float4 e = {-1e30f, -1e30f, -1e30f, -1e30f};
    if (lane < deg) {
        e.x = lrelu(as4.x + ad.x);
        e.y = lrelu(as4.y + ad.y);
        e.z = lrelu(as4.z + ad.z);
        e.w = lrelu(as4.w + ad.w);
    }
    float4 m = e;
#pragma unroll
    for (int off = 1; off < 64; off <<= 1) {
        m.x = fmaxf(m.x, __shfl_xor(m.x, off));
        m.y = fmaxf(m.y, __shfl_xor(m.y, off));
        m.z = fmaxf(m.z, __shfl_xor(m.z, off));
        m.w = fmaxf(m.w, __shfl_xor(m.w, off));
    }
    float4 wgt = {0, 0, 0, 0};
    if (lane < deg) {
        wgt.x = __expf(e.x - m.x); wgt.y = __expf(e.y - m.y);
        wgt.z = __expf(e.z - m.z); wgt.w = __expf(e.w - m.w);
    }
    float4 s = wgt;
#pragma unroll
    for (int off = 1; off < 64; off <<= 1) {
        s.x += __shfl_xor(s.x, off); s.y += __shfl_xor(s.y, off);
        s.z += __shfl_xor(s.z, off); s.w += __shfl_xor(s.w, off);
    }
    s_src[lane] = (unsigned short)src;
    s_alpha[lane][0] = wgt.x / s.x;
    s_alpha[lane][1] = wgt.y / s.y;
    s_alpha[lane][2] = wgt.z / s.z;
    s_alpha[lane][3] = wgt.w / s.w;
    __syncthreads();                   // single-wave: waitcnt + cheap barrier

    float acc[8];
#pragma unroll
    for (int k = 0; k < 8; ++k) acc[k] = 0.f;

    const int mde = (deg + 1) & ~1;
    int j = 0;
    if (mde >= 8) {                    // consume the prefetched burst
        const float a0 = s_alpha[half][head];
        const float a1 = s_alpha[2 + half][head];
        const float a2 = s_alpha[4 + half][head];
        const float a3 = s_alpha[6 + half][head];
#pragma unroll
        for (int k = 0; k < 8; ++k)
            acc[k] += a0 * (float)hp0[k] + a1 * (float)hp1[k]
                    + a2 * (float)hp2[k] + a3 * (float)hp3[k];
        j = 8;
        for (; j + 8 <= mde; j += 8) {   // 8 sources in flight (4 loads/half)
            int j0 = j + half, j1 = j + 2 + half, j2 = j + 4 + half, j3 = j + 6 + half;
            int s0 = s_src[j0], s1 = s_src[j1], s2 = s_src[j2], s3 = s_src[j3];
            float b0 = s_alpha[j0][head], b1 = s_alpha[j1][head];
            float b2 = s_alpha[j2][head], b3 = s_alpha[j3][head];
            bf16x8 h0 = *(const bf16x8*)&h[(size_t)s0 * HD + c0];
            bf16x8 h1 = *(const bf16x8*)&h[(size_t)s1 * HD + c0];
            bf16x8 h2 = *(const bf16x8*)&h[(size_t)s2 * HD + c0];
            bf16x8 h3 = *(const bf16x8*)&h[(size_t)s3 * HD + c0];
#pragma unroll
            for (int k = 0; k < 8; ++k)
                acc[k] += b0 * (float)h0[k] + b1 * (float)h1[k]
                        + b2 * (float)h2[k] + b3 * (float)h3[k];
        }
    }
    for (; j < mde; j += 2) {
        int j0 = j + half;
        int s0 = s_src[j0];
        float a0 = s_alpha[j0][head];
        bf16x8 h0 = *(const bf16x8*)&h[(size_t)s0 * HD + c0];
#pragma unroll
        for (int k = 0; k < 8; ++k)
            acc[k] += a0 * (float)h0[k];
    }
    // combine the two halves
#pragma unroll
    for (int k = 0; k < 8; ++k) acc[k] += __shfl_xor(acc[k], 32);

    if (half == 0) {
        float4 bg0 = *(const float4*)&b_gat[c0];
        float4 bg1 = *(const float4*)&b_gat[c0 + 4];
        bf16x8 o;
        o[0] = (__bf16)(acc[0] + bg0.x); o[1] = (__bf16)(acc[1] + bg0.y);
        o[2] = (__bf16)(acc[2] + bg0.z); o[3] = (__bf16)(acc[3] + bg0.w);
        o[4] = (__bf16)(acc[4] + bg1.x); o[5] = (__bf16)(acc[5] + bg1.y);
        o[6] = (__bf16)(acc[6] + bg1.z); o[7] = (__bf16)(acc[7] + bg1.w);
        *(bf16x8*)&gat[(size_t)n * HD + c0] = o;
    }
}

// ---------------------------------------------------------------------------
// Fused MLP: out = relu(relu(gat@W1+b1)@W2+b2)@W3 + b3, one kernel.
__global__ __launch_bounds__(256) void fused_mlp_kernel(const __bf16* __restrict__ A,
                                                        const __bf16* __restrict__ W1t,
                                                        const __bf16* __restrict__ W2t,
                                                        const float* __restrict__ b1,
                                                        const float* __restrict__ b2,
                                                        const float* __restrict__ W3,
                                                        const float* __restrict__ b3,
                                                        float* __restrict__ out) {
    __shared__ __bf16 As[64 * 32];        // 4 KB
    __shared__ __bf16 Ws[256 * 32];       // 16 KB
    __shared__ __bf16 h1s[8 * 64 * 32];   // 32 KB, chunk c holds k in [32c,32c+32)
    __shared__ float s_out[64][2];
    const int t = threadIdx.x;
    const int lane = t & 63, wv = t >> 6;
    const int lr = lane & 15, q = lane >> 4, lk = q * 8;
    const int col_off = wv * 64;
    const int row0 = blockIdx.x * 64;
    const int sr = t >> 2, sk = (t & 3) * 8;

    if (t < 128) ((float*)s_out)[t] = 0.f;

    f32x4 acc[4][4];
#pragma unroll
    for (int r = 0; r < 4; ++r)
#pragma unroll
        for (int c = 0; c < 4; ++c) acc[r][c] = f32x4{0.f, 0.f, 0.f, 0.f};

    // ---- stage 1: h1 = relu(gat @ W1 + b1) -> LDS
    for (int k0 = 0; k0 < HD; k0 += 32) {
        GLD_LDS16(&A[(size_t)(row0 + sr) * HD + k0 + sk], &As[sr * 32 + sk]);
#pragma unroll
        for (int s = 0; s < 4; ++s) {
            int r = s * 64 + sr;
            GLD_LDS16(&W1t[(size_t)r * HD + k0 + sk], &Ws[r * 32 + sk]);
        }
        __syncthreads();
        bf16x8 af[4], bfr[4];
#pragma unroll
        for (int i = 0; i < 4; ++i) {
            af[i]  = *(const bf16x8*)&As[(i * 16 + lr) * 32 + lk];
            bfr[i] = *(const bf16x8*)&Ws[(col_off + i * 16 + lr) * 32 + lk];
        }
#pragma unroll
        for (int r = 0; r < 4; ++r)
#pragma unroll
            for (int c = 0; c < 4; ++c)
                acc[r][c] = __builtin_amdgcn_mfma_f32_16x16x32_bf16(af[r], bfr[c], acc[r][c], 0, 0, 0);
        __syncthreads();
    }
#pragma unroll
    for (int c = 0; c < 4; ++c) {
        int col = col_off + c * 16 + lr;
        float bv = b1[col];
        int cb = (col >> 5) * 2048;
        int kk = col & 31;
#pragma unroll
        for (int r = 0; r < 4; ++r)
#pragma unroll
            for (int i = 0; i < 4; ++i) {
                int row = r * 16 + q * 4 + i;
                float v = fmaxf(acc[r][c][i] + bv, 0.f);
                h1s[cb + row * 32 + kk] = (__bf16)v;
                acc[r][c][i] = 0.f;
            }
    }
    __syncthreads();

    // ---- stage 2: h2 = h1 @ W2
    for (int k0 = 0; k0 < HID; k0 += 32) {
#pragma unroll
        for (int s = 0; s < 4; ++s) {
            int r = s * 64 + sr;
            GLD_LDS16(&W2t[(size_t)r * HID + k0 + sk], &Ws[r * 32 + sk]);
        }
        __syncthreads();
        const int cb = (k0 >> 5) * 2048;
        bf16x8 af[4], bfr[4];
#pragma unroll
        for (int i = 0; i < 4; ++i) {
            af[i]  = *(const bf16x8*)&h1s[cb + (i * 16 + lr) * 32 + lk];
            bfr[i] = *(const bf16x8*)&Ws[(col_off + i * 16 + lr) * 32 + lk];
        }
#pragma unroll
        for (int r = 0; r < 4; ++r)
#pragma unroll
            for (int c = 0; c < 4; ++c)
                acc[r][c] = __builtin_amdgcn_mfma_f32_16x16x32_bf16(af[r], bfr[c], acc[r][c], 0, 0, 0);
        __syncthreads();
    }

    // ---- stage 3: out = relu(h2+b2) @ W3 + b3 (fp32 throughout)
    float b2v[4], w30[4], w31[4];
#pragma unroll
    for (int c = 0; c < 4; ++c) {
        int col = col_off + c * 16 + lr;
        b2v[c] = b2[col];
        w30[c] = W3[col * 2];
        w31[c] = W3[col * 2 + 1];
    }
#pragma unroll
    for (int r = 0; r < 4; ++r) {
#pragma unroll
        for (int i = 0; i < 4; ++i) {
            float o0 = 0.f, o1 = 0.f;
#pragma unroll
            for (int c = 0; c < 4; ++c) {
                float v = fmaxf(acc[r][c][i] + b2v[c], 0.f);
                o0 += v * w30[c];
                o1 += v * w31[c];
            }
#pragma unroll
            for (int m = 1; m < 16; m <<= 1) {
                o0 += __shfl_xor(o0, m);
                o1 += __shfl_xor(o1, m);
            }
            if (lr == 0) {
                int row = r * 16 + q * 4 + i;
                atomicAdd(&s_out[row][0], o0);
                atomicAdd(&s_out[row][1], o1);
            }
        }
    }
    __syncthreads();
    if (t < 128) {
        int row = t >> 1, o = t & 1;
        int g = row0 + row;
        if (g < N_NODES) out[g * 2 + o] = s_out[row][o] + b3[o];
    }
}

// ---------------------------------------------------------------------------
extern "C" void kernel_launch(void* const* d_in, const int* in_sizes, int n_in,
                              void* d_out, int out_size, void* d_ws, size_t ws_size,
                              hipStream_t stream) {
    const float* x       = (const float*)d_in[0];
    const int*   ei      = (const int*)d_in[1];
    const float* W_gat   = (const float*)d_in[2];
    const float* att_src = (const float*)d_in[3];
    const float* att_dst = (const float*)d_in[4];
    const float* b_gat   = (const float*)d_in[5];
    const float* W1      = (const float*)d_in[6];
    const float* b1      = (const float*)d_in[7];
    const float* W2      = (const float*)d_in[8];
    const float* b2      = (const float*)d_in[9];
    const float* W3      = (const float*)d_in[10];
    const float* b3      = (const float*)d_in[11];
    float* out = (float*)d_out;

    char* ws = (char*)d_ws;
    __bf16* h_bf   = (__bf16*)ws;  ws += (size_t)NP * HD * 2;
    __bf16* gat_bf = (__bf16*)ws;  ws += (size_t)NP * HD * 2;
    __bf16* Wg_t   = (__bf16*)ws;  ws += (size_t)HD * F_IN * 2;
    __bf16* W1_t   = (__bf16*)ws;  ws += (size_t)HID * HD * 2;
    __bf16* W2_t   = (__bf16*)ws;  ws += (size_t)HID * HID * 2;
    float* a_s     = (float*)ws;   ws += (size_t)NP * 4 * 4;
    float* a_d     = (float*)ws;   ws += (size_t)NP * 4 * 4;
    int* cnt       = (int*)ws;     ws += (size_t)N_NODES * CNT_STRIDE * 4;
    unsigned short* bucket = (unsigned short*)ws;
    ws += (size_t)N_NODES * CAP * 2;

    prep_kernel<<<PB_INIT + PB_WG + PB_W1 + PB_W2, 256, 0, stream>>>(
        W_gat, W1, W2, Wg_t, W1_t, W2_t, cnt, bucket);
    g1_fill_kernel<<<G1_BLOCKS + FILL_BLOCKS, 256, 0, stream>>>(
        x, Wg_t, att_src, att_dst, ei, h_bf, a_s, a_d, cnt, bucket);
    gat_aggregate_kernel<<<N_NODES, 64, 0, stream>>>(h_bf, a_s, a_d, cnt, bucket,
                                                     b_gat, gat_bf);
    fused_mlp_kernel<<<NP / 64, 256, 0, stream>>>(gat_bf, W1_t, W2_t, b1, b2, W3, b3, out);
}